// Round 3
// baseline (454.591 us; speedup 1.0000x reference)
//
#include <hip/hip_runtime.h>

#define MEM    150
#define GW     640   // 4 gates interleaved: col = 4*j + g
#define KX     300   // x-proj real K
#define KXP    320   // x-proj padded K (bf16 A buffer pitch)
#define KH     160   // level GEMM K (padded, H buffer is pre-padded)
#define NLEAF  65536
#define NTOT   87381
#define DEPTH  9

static const int SIZES[DEPTH] = {65536,16384,4096,1024,256,64,16,4,1};
static const int OFF[DEPTH]   = {0,65536,81920,86016,87040,87296,87360,87376,87380};

typedef __attribute__((ext_vector_type(8))) short short8;
typedef __attribute__((ext_vector_type(4))) float f32x4;

__device__ __forceinline__ float sigf(float x) { return 1.0f / (1.0f + __expf(-x)); }
__device__ __forceinline__ float tanhf_fast(float x) {
    float e = __expf(2.0f * x);
    return 1.0f - 2.0f / (e + 1.0f);
}
__device__ __forceinline__ unsigned short f2bf(float f) {
    union { float f; unsigned u; } v; v.f = f;
    unsigned r = v.u + 0x7FFF + ((v.u >> 16) & 1);
    return (unsigned short)(r >> 16);
}
__device__ __forceinline__ float bf2f(unsigned short u) {
    union { unsigned u; float f; } v; v.u = ((unsigned)u) << 16; return v.f;
}

typedef const __attribute__((address_space(1))) unsigned int* as1_u32p;
typedef __attribute__((address_space(3))) unsigned int* as3_u32p;
__device__ __forceinline__ void gl_lds16(const unsigned short* g, unsigned short* l) {
    __builtin_amdgcn_global_load_lds((as1_u32p)g, (as3_u32p)l, 16, 0, 0);
}

__device__ __forceinline__ short8 sum4bf(short8 a, short8 b, short8 c, short8 d) {
    short8 r;
    #pragma unroll
    for (int e = 0; e < 8; ++e) {
        float s = bf2f((unsigned short)a[e]) + bf2f((unsigned short)b[e])
                + bf2f((unsigned short)c[e]) + bf2f((unsigned short)d[e]);
        r[e] = (short)f2bf(s);
    }
    return r;
}

// ---------------- prep: weight packing + embs conversion (one dispatch) --------
// W4xT: 640 x KXP, row c=4j+g from W_gx[k][j]   (g: 0=i,1=f,2=u,3=o)
// W4hT: 640 x KH, same layout (tail levels)
// WfhT: 256 x KH (f-gate only, row c=j)
// W3hT: 640 x KH, row c=4j+g with g: 0=Wih,1=Wuh,2=Woh,3=zero
__global__ void prep(const float* __restrict__ Wix, const float* __restrict__ Wfx,
                     const float* __restrict__ Wux, const float* __restrict__ Wox,
                     const float* __restrict__ bix, const float* __restrict__ bfx,
                     const float* __restrict__ bux, const float* __restrict__ box,
                     const float* __restrict__ Wih, const float* __restrict__ Wfh,
                     const float* __restrict__ Wuh, const float* __restrict__ Woh,
                     const float* __restrict__ bih, const float* __restrict__ bfh,
                     const float* __restrict__ buh, const float* __restrict__ boh,
                     const float* __restrict__ embs,
                     unsigned short* __restrict__ W4xT, unsigned short* __restrict__ W4hT,
                     unsigned short* __restrict__ WfhT, unsigned short* __restrict__ W3hT,
                     float* __restrict__ b4x, float* __restrict__ b4hf,
                     float* __restrict__ bfhb, float* __restrict__ b3h,
                     unsigned short* __restrict__ Abf)
{
    if (blockIdx.x < 256) {
        int tid = blockIdx.x * 256 + threadIdx.x;
        const int stride = 256 * 256;
        for (int idx = tid; idx < GW * KXP; idx += stride) {
            int c = idx / KXP, k = idx - c * KXP;
            int j = c >> 2, g = c & 3;
            const float* W = (g == 0) ? Wix : (g == 1) ? Wfx : (g == 2) ? Wux : Wox;
            W4xT[idx] = (j < MEM && k < KX) ? f2bf(W[k * MEM + j]) : (unsigned short)0;
        }
        for (int idx = tid; idx < GW * KH; idx += stride) {
            int c = idx / KH, k = idx - c * KH;
            int j = c >> 2, g = c & 3;
            const float* W = (g == 0) ? Wih : (g == 1) ? Wfh : (g == 2) ? Wuh : Woh;
            W4hT[idx] = (j < MEM && k < MEM) ? f2bf(W[k * MEM + j]) : (unsigned short)0;
        }
        for (int idx = tid; idx < 256 * KH; idx += stride) {
            int c = idx / KH, k = idx - c * KH;
            WfhT[idx] = (c < MEM && k < MEM) ? f2bf(Wfh[k * MEM + c]) : (unsigned short)0;
        }
        for (int idx = tid; idx < GW * KH; idx += stride) {
            int c = idx / KH, k = idx - c * KH;
            int j = c >> 2, g = c & 3;
            unsigned short v = 0;
            if (g < 3 && j < MEM && k < MEM) {
                const float* W = (g == 0) ? Wih : (g == 1) ? Wuh : Woh;
                v = f2bf(W[k * MEM + j]);
            }
            W3hT[idx] = v;
        }
        for (int idx = tid; idx < GW; idx += stride) {
            int j = idx >> 2, g = idx & 3;
            const float* b = (g == 0) ? bix : (g == 1) ? bfx : (g == 2) ? bux : box;
            b4x[idx]  = (j < MEM) ? b[j] : 0.0f;
            b4hf[idx] = (g == 1 && j < MEM) ? bfh[j] : 0.0f;
            float v3 = 0.0f;
            if (g < 3 && j < MEM) v3 = (g == 0) ? bih[j] : (g == 1) ? buh[j] : boh[j];
            b3h[idx] = v3;
        }
        for (int idx = tid; idx < 256; idx += stride)
            bfhb[idx] = (idx < MEM) ? bfh[idx] : 0.0f;
    } else {
        int idx = (blockIdx.x - 256) * 256 + threadIdx.x;
        if (idx >= NTOT * (KXP / 8)) return;
        int n = idx / (KXP / 8), c = idx - n * (KXP / 8);
        int c0 = c * 8;
        unsigned short v[8];
        if (c0 + 8 <= KX) {
            const float4* p = (const float4*)(embs + (size_t)n * KX + c0);
            float4 f0 = p[0], f1 = p[1];
            v[0]=f2bf(f0.x); v[1]=f2bf(f0.y); v[2]=f2bf(f0.z); v[3]=f2bf(f0.w);
            v[4]=f2bf(f1.x); v[5]=f2bf(f1.y); v[6]=f2bf(f1.z); v[7]=f2bf(f1.w);
        } else {
            const float* row = embs + (size_t)n * KX;
            #pragma unroll
            for (int j = 0; j < 8; ++j) {
                int col = c0 + j;
                v[j] = (col < KX) ? f2bf(row[col]) : (unsigned short)0;
            }
        }
        *(short8*)&Abf[(size_t)n * KXP + c0] = *(short8*)v;
    }
}

// ---------------- bf16 MFMA GEMM (gl_lds staging), leaf-fused for xproj --------
template<int KPAD, bool FUSE>
__global__ __launch_bounds__(256) void gemm_lds(
    const unsigned short* __restrict__ A, int M,
    const unsigned short* __restrict__ BT,
    const float* __restrict__ bias,
    unsigned short* __restrict__ Cout, int pitch, int nValid, int ntl,
    const float* __restrict__ bih, const float* __restrict__ buh,
    const float* __restrict__ boh,
    float* __restrict__ outLeaf, float* __restrict__ CLeaf,
    unsigned short* __restrict__ HbfLeaf)
{
    __shared__ __align__(16) unsigned short lds[16384];

    const int nwg = gridDim.x;
    const int orig = blockIdx.x;
    const int qq = nwg >> 3, rr = nwg & 7;
    const int xcd = orig & 7, lin = orig >> 3;
    const int dd = (xcd < rr ? xcd * (qq + 1) : rr * (qq + 1) + (xcd - rr) * qq) + lin;
    const int mtile = dd / ntl, ntile = dd - mtile * ntl;

    const int t = threadIdx.x;
    const int m0 = mtile * 128, n0 = ntile * 128;
    const int l = t & 63, w = t >> 6;
    const int l15 = l & 15, q = l >> 4;
    const int wm = (w & 1) * 64, wn = (w >> 1) * 64;

    const int srow = t >> 2;
    const int scol = ((t & 3) ^ (srow & 3)) * 8;
    int gr0 = m0 + srow;      if (gr0 >= M) gr0 = M - 1;
    int gr1 = m0 + 64 + srow; if (gr1 >= M) gr1 = M - 1;
    const unsigned short* a0 = A + (size_t)gr0 * KPAD + scol;
    const unsigned short* a1 = A + (size_t)gr1 * KPAD + scol;
    const unsigned short* b0 = BT + (size_t)(n0 + srow) * KPAD + scol;
    const unsigned short* b1 = BT + (size_t)(n0 + 64 + srow) * KPAD + scol;

    f32x4 acc[4][4];
    #pragma unroll
    for (int i = 0; i < 4; ++i)
        #pragma unroll
        for (int j = 0; j < 4; ++j)
            acc[i][j] = (f32x4){0.f, 0.f, 0.f, 0.f};

    const int kiters = KPAD >> 5;
    unsigned short* As = lds;
    unsigned short* Bs = lds + 8192;
    gl_lds16(a0, As + t * 8);
    gl_lds16(a1, As + 2048 + t * 8);
    gl_lds16(b0, Bs + t * 8);
    gl_lds16(b1, Bs + 2048 + t * 8);
    __syncthreads();

    int cur = 0;
    for (int kt = 0; kt < kiters; ++kt) {
        if (kt + 1 < kiters) {
            const int ko = (kt + 1) << 5;
            const int nb = cur ^ 1;
            gl_lds16(a0 + ko, As + nb * 4096 + t * 8);
            gl_lds16(a1 + ko, As + nb * 4096 + 2048 + t * 8);
            gl_lds16(b0 + ko, Bs + nb * 4096 + t * 8);
            gl_lds16(b1 + ko, Bs + nb * 4096 + 2048 + t * 8);
        }
        short8 a[4], b[4];
        const int csw = (q ^ (l15 & 3)) * 8;
        #pragma unroll
        for (int i = 0; i < 4; ++i)
            a[i] = *(const short8*)&As[cur * 4096 + (wm + i * 16 + l15) * 32 + csw];
        #pragma unroll
        for (int j = 0; j < 4; ++j)
            b[j] = *(const short8*)&Bs[cur * 4096 + (wn + j * 16 + l15) * 32 + csw];
        #pragma unroll
        for (int i = 0; i < 4; ++i)
            #pragma unroll
            for (int j = 0; j < 4; ++j)
                acc[i][j] = __builtin_amdgcn_mfma_f32_16x16x32_bf16(a[i], b[j], acc[i][j], 0, 0, 0);
        __syncthreads();
        cur ^= 1;
    }

    float bj[4];
    #pragma unroll
    for (int j = 0; j < 4; ++j) bj[j] = bias[n0 + wn + j * 16 + l15];
    #pragma unroll
    for (int i = 0; i < 4; ++i)
        #pragma unroll
        for (int j = 0; j < 4; ++j)
            #pragma unroll
            for (int r = 0; r < 4; ++r)
                lds[(wm + i * 16 + q * 4 + r) * 128 + wn + j * 16 + l15] =
                    f2bf(acc[i][j][r] + bj[j]);
    __syncthreads();

    if (FUSE && m0 < NLEAF) {
        #pragma unroll
        for (int s = 0; s < 16; ++s) {
            int idx = (s << 8) + t;
            int row = idx >> 5, jl = idx & 31;
            int grow = m0 + row;
            int j = ntile * 32 + jl;
            const unsigned short* g4 = &lds[row * 128 + jl * 4];
            if (j < MEM) {
                float gi = bf2f(g4[0]) + bih[j];
                float gu = bf2f(g4[2]) + buh[j];
                float go = bf2f(g4[3]) + boh[j];
                float iv = sigf(gi), uv = tanhf_fast(gu), ov = sigf(go);
                float c = iv * uv;
                float h = ov * tanhf_fast(c);
                outLeaf[(size_t)grow * MEM + j] = h;
                CLeaf[(size_t)grow * MEM + j] = c;
                HbfLeaf[(size_t)grow * KH + j] = f2bf(h);
            } else if (j < KH) {
                HbfLeaf[(size_t)grow * KH + j] = 0;
            }
        }
    } else {
        int row = t >> 1, half = t & 1;
        int grow = m0 + row;
        if (grow < M) {
            const unsigned short* src = &lds[row * 128 + half * 64];
            unsigned short* dst = Cout + (size_t)grow * pitch + n0 + half * 64;
            #pragma unroll
            for (int c8 = 0; c8 < 8; ++c8) {
                int col0 = n0 + half * 64 + c8 * 8;
                if (col0 < nValid)
                    *(short8*)(dst + c8 * 8) = *(const short8*)(src + c8 * 8);
            }
        }
    }
}

// ---------------- iuo-GEMM with on-the-fly hsum + fused cell epilogue ----------
// A row (parent nn) = sum of 4 child rows of Hprev (bf16-rounded, = old hsum_k).
// B = W3hT (640 x KH, col layout 4f+{i,u,o,pad}, biases in b3h).
// Epilogue computes the full cell using P (x-proj), Gf (per-child f preacts,
// written by the stream-previous f-GEMM), Cprev; writes out/C/Hbf.
__global__ __launch_bounds__(256) void gemm_iuo(
    const unsigned short* __restrict__ Hprev, int n,
    const unsigned short* __restrict__ W3hT, const float* __restrict__ b3h,
    const unsigned short* __restrict__ Gf,
    const unsigned short* __restrict__ P,
    const float* __restrict__ Cprev,
    float* __restrict__ outRow, float* __restrict__ Crow,
    unsigned short* __restrict__ HbfRow)
{
    __shared__ __align__(16) unsigned short lds[16384];
    unsigned short* As = lds;
    unsigned short* Bs = lds + 8192;

    const int nwg = gridDim.x;
    const int orig = blockIdx.x;
    const int qq = nwg >> 3, rr = nwg & 7;
    const int xcd = orig & 7, lin = orig >> 3;
    const int dd = (xcd < rr ? xcd * (qq + 1) : rr * (qq + 1) + (xcd - rr) * qq) + lin;
    const int mtile = dd / 5, ntile = dd - mtile * 5;

    const int t = threadIdx.x;
    const int m0 = mtile * 128, n0 = ntile * 128;
    const int l = t & 63, w = t >> 6;
    const int l15 = l & 15, q = l >> 4;
    const int wm = (w & 1) * 64, wn = (w >> 1) * 64;

    const int srow = t >> 2;
    const int scol = ((t & 3) ^ (srow & 3)) * 8;
    int gp0 = m0 + srow;      if (gp0 >= n) gp0 = n - 1;
    int gp1 = m0 + 64 + srow; if (gp1 >= n) gp1 = n - 1;
    const unsigned short* a0 = Hprev + (size_t)(4 * gp0) * KH + scol;
    const unsigned short* a1 = Hprev + (size_t)(4 * gp1) * KH + scol;
    const unsigned short* b0 = W3hT + (size_t)(n0 + srow) * KH + scol;
    const unsigned short* b1 = W3hT + (size_t)(n0 + 64 + srow) * KH + scol;

    f32x4 acc[4][4];
    #pragma unroll
    for (int i = 0; i < 4; ++i)
        #pragma unroll
        for (int j = 0; j < 4; ++j)
            acc[i][j] = (f32x4){0.f, 0.f, 0.f, 0.f};

    // prologue: stage tile 0 (A via reg-sum of 4 child rows, B via gl_lds)
    {
        short8 r0 = *(const short8*)(a0);
        short8 r1 = *(const short8*)(a0 + KH);
        short8 r2 = *(const short8*)(a0 + 2 * KH);
        short8 r3 = *(const short8*)(a0 + 3 * KH);
        short8 s0 = *(const short8*)(a1);
        short8 s1 = *(const short8*)(a1 + KH);
        short8 s2 = *(const short8*)(a1 + 2 * KH);
        short8 s3 = *(const short8*)(a1 + 3 * KH);
        gl_lds16(b0, Bs + t * 8);
        gl_lds16(b1, Bs + 2048 + t * 8);
        *(short8*)&As[t * 8]        = sum4bf(r0, r1, r2, r3);
        *(short8*)&As[2048 + t * 8] = sum4bf(s0, s1, s2, s3);
    }
    __syncthreads();

    const int kiters = KH >> 5;   // 5
    int cur = 0;
    for (int kt = 0; kt < kiters; ++kt) {
        short8 r0, r1, r2, r3, s0, s1, s2, s3;
        const int nb = cur ^ 1;
        const bool pre = (kt + 1 < kiters);
        if (pre) {
            const int ko = (kt + 1) << 5;
            r0 = *(const short8*)(a0 + ko);
            r1 = *(const short8*)(a0 + ko + KH);
            r2 = *(const short8*)(a0 + ko + 2 * KH);
            r3 = *(const short8*)(a0 + ko + 3 * KH);
            s0 = *(const short8*)(a1 + ko);
            s1 = *(const short8*)(a1 + ko + KH);
            s2 = *(const short8*)(a1 + ko + 2 * KH);
            s3 = *(const short8*)(a1 + ko + 3 * KH);
            gl_lds16(b0 + ko, Bs + nb * 4096 + t * 8);
            gl_lds16(b1 + ko, Bs + nb * 4096 + 2048 + t * 8);
        }
        short8 a[4], b[4];
        const int csw = (q ^ (l15 & 3)) * 8;
        #pragma unroll
        for (int i = 0; i < 4; ++i)
            a[i] = *(const short8*)&As[cur * 4096 + (wm + i * 16 + l15) * 32 + csw];
        #pragma unroll
        for (int j = 0; j < 4; ++j)
            b[j] = *(const short8*)&Bs[cur * 4096 + (wn + j * 16 + l15) * 32 + csw];
        #pragma unroll
        for (int i = 0; i < 4; ++i)
            #pragma unroll
            for (int j = 0; j < 4; ++j)
                acc[i][j] = __builtin_amdgcn_mfma_f32_16x16x32_bf16(a[i], b[j], acc[i][j], 0, 0, 0);
        if (pre) {
            *(short8*)&As[nb * 4096 + t * 8]        = sum4bf(r0, r1, r2, r3);
            *(short8*)&As[nb * 4096 + 2048 + t * 8] = sum4bf(s0, s1, s2, s3);
        }
        __syncthreads();
        cur ^= 1;
    }

    // epilogue: transpose via LDS, then fused cell
    float bj[4];
    #pragma unroll
    for (int j = 0; j < 4; ++j) bj[j] = b3h[n0 + wn + j * 16 + l15];
    #pragma unroll
    for (int i = 0; i < 4; ++i)
        #pragma unroll
        for (int j = 0; j < 4; ++j)
            #pragma unroll
            for (int r = 0; r < 4; ++r)
                lds[(wm + i * 16 + q * 4 + r) * 128 + wn + j * 16 + l15] =
                    f2bf(acc[i][j][r] + bj[j]);
    __syncthreads();

    #pragma unroll
    for (int s = 0; s < 16; ++s) {
        int idx = (s << 8) + t;
        int row = idx >> 5, jl = idx & 31;
        int grow = m0 + row;
        if (grow >= n) continue;
        int j = (n0 >> 2) + jl;
        if (j < MEM) {
            const unsigned short* g3 = &lds[row * 128 + jl * 4];
            const unsigned short* xr = P + (size_t)grow * GW + 4 * j;
            float iv = sigf(bf2f(xr[0]) + bf2f(g3[0]));
            float uv = tanhf_fast(bf2f(xr[2]) + bf2f(g3[1]));
            float ov = sigf(bf2f(xr[3]) + bf2f(g3[2]));
            float xf = bf2f(xr[1]);
            float fc = 0.0f;
            #pragma unroll
            for (int k = 0; k < 4; ++k) {
                float f = sigf(xf + bf2f(Gf[(size_t)(4 * grow + k) * KH + j]));
                fc += f * Cprev[(size_t)(4 * grow + k) * MEM + j];
            }
            float c = iv * uv + fc;
            float h = ov * tanhf_fast(c);
            outRow[(size_t)grow * MEM + j] = h;
            Crow[(size_t)grow * MEM + j] = c;
            HbfRow[(size_t)grow * KH + j] = f2bf(h);
        } else if (j < KH) {
            HbfRow[(size_t)grow * KH + j] = 0;
        }
    }
}

// ---------------- tail level: one dispatch, 5 blocks, GEMM + cell --------------
// Block ntile owns cols [128*ntile, +128) = features [32*ntile, +32). It
// computes per-child 4-gate preacts for ALL nprev children (m-chunks of 128,
// sequential) into Gc, then the cell for its features over all n parents.
__global__ __launch_bounds__(256) void tail_level(
    const unsigned short* __restrict__ Hprev, int nprev, int n,
    const unsigned short* __restrict__ W4hT, const float* __restrict__ b4hf,
    unsigned short* __restrict__ Gc,
    const unsigned short* __restrict__ P,
    const float* __restrict__ Cprev,
    const float* __restrict__ bih, const float* __restrict__ buh,
    const float* __restrict__ boh,
    float* __restrict__ outRow, float* __restrict__ Crow,
    unsigned short* __restrict__ HbfRow)
{
    __shared__ __align__(16) unsigned short lds[16384];
    unsigned short* As = lds;
    unsigned short* Bs = lds + 8192;
    const int ntile = blockIdx.x;
    const int n0 = ntile * 128;
    const int t = threadIdx.x;
    const int l = t & 63, w = t >> 6;
    const int l15 = l & 15, q = l >> 4;
    const int wm = (w & 1) * 64, wn = (w >> 1) * 64;
    const int srow = t >> 2;
    const int scol = ((t & 3) ^ (srow & 3)) * 8;
    const unsigned short* b0 = W4hT + (size_t)(n0 + srow) * KH + scol;
    const unsigned short* b1 = W4hT + (size_t)(n0 + 64 + srow) * KH + scol;

    const int mchunks = (nprev + 127) >> 7;
    for (int mc = 0; mc < mchunks; ++mc) {
        const int m0 = mc * 128;
        int gr0 = m0 + srow;      if (gr0 >= nprev) gr0 = nprev - 1;
        int gr1 = m0 + 64 + srow; if (gr1 >= nprev) gr1 = nprev - 1;
        const unsigned short* a0 = Hprev + (size_t)gr0 * KH + scol;
        const unsigned short* a1 = Hprev + (size_t)gr1 * KH + scol;

        f32x4 acc[4][4];
        #pragma unroll
        for (int i = 0; i < 4; ++i)
            #pragma unroll
            for (int j = 0; j < 4; ++j)
                acc[i][j] = (f32x4){0.f, 0.f, 0.f, 0.f};

        gl_lds16(a0, As + t * 8);
        gl_lds16(a1, As + 2048 + t * 8);
        gl_lds16(b0, Bs + t * 8);
        gl_lds16(b1, Bs + 2048 + t * 8);
        __syncthreads();

        int cur = 0;
        for (int kt = 0; kt < (KH >> 5); ++kt) {
            if (kt + 1 < (KH >> 5)) {
                const int ko = (kt + 1) << 5;
                const int nb = cur ^ 1;
                gl_lds16(a0 + ko, As + nb * 4096 + t * 8);
                gl_lds16(a1 + ko, As + nb * 4096 + 2048 + t * 8);
                gl_lds16(b0 + ko, Bs + nb * 4096 + t * 8);
                gl_lds16(b1 + ko, Bs + nb * 4096 + 2048 + t * 8);
            }
            short8 a[4], b[4];
            const int csw = (q ^ (l15 & 3)) * 8;
            #pragma unroll
            for (int i = 0; i < 4; ++i)
                a[i] = *(const short8*)&As[cur * 4096 + (wm + i * 16 + l15) * 32 + csw];
            #pragma unroll
            for (int j = 0; j < 4; ++j)
                b[j] = *(const short8*)&Bs[cur * 4096 + (wn + j * 16 + l15) * 32 + csw];
            #pragma unroll
            for (int i = 0; i < 4; ++i)
                #pragma unroll
                for (int j = 0; j < 4; ++j)
                    acc[i][j] = __builtin_amdgcn_mfma_f32_16x16x32_bf16(a[i], b[j], acc[i][j], 0, 0, 0);
            __syncthreads();
            cur ^= 1;
        }

        float bj[4];
        #pragma unroll
        for (int j = 0; j < 4; ++j) bj[j] = b4hf[n0 + wn + j * 16 + l15];
        #pragma unroll
        for (int i = 0; i < 4; ++i)
            #pragma unroll
            for (int r = 0; r < 4; ++r) {
                int grow = m0 + wm + i * 16 + q * 4 + r;
                unsigned short* crow = Gc + (size_t)grow * GW;
                #pragma unroll
                for (int j = 0; j < 4; ++j)
                    crow[n0 + wn + j * 16 + l15] = f2bf(acc[i][j][r] + bj[j]);
            }
        __syncthreads();
    }

    // cell phase for this block's 32 features over all n parents
    const int total = n * 32;
    for (int idx = t; idx < total; idx += 256) {
        int par = idx >> 5, jl = idx & 31;
        int j = (n0 >> 2) + jl;
        if (j < MEM) {
            const unsigned short* xr = P + (size_t)par * GW + 4 * j;
            float ip = bf2f(xr[0]) + bih[j];
            float xf = bf2f(xr[1]);
            float up = bf2f(xr[2]) + buh[j];
            float op = bf2f(xr[3]) + boh[j];
            float fc = 0.0f;
            #pragma unroll
            for (int k = 0; k < 4; ++k) {
                const unsigned short* gk = Gc + (size_t)(4 * par + k) * GW + 4 * j;
                ip += bf2f(gk[0]);
                up += bf2f(gk[2]);
                op += bf2f(gk[3]);
                float f = sigf(xf + bf2f(gk[1]));
                fc += f * Cprev[(size_t)(4 * par + k) * MEM + j];
            }
            float iv = sigf(ip), uv = tanhf_fast(up), ov = sigf(op);
            float c = iv * uv + fc;
            float h = ov * tanhf_fast(c);
            outRow[(size_t)par * MEM + j] = h;
            Crow[(size_t)par * MEM + j] = c;
            HbfRow[(size_t)par * KH + j] = f2bf(h);
        } else if (j < KH) {
            HbfRow[(size_t)par * KH + j] = 0;
        }
    }
}

extern "C" void kernel_launch(void* const* d_in, const int* in_sizes, int n_in,
                              void* d_out, int out_size, void* d_ws, size_t ws_size,
                              hipStream_t stream)
{
    (void)in_sizes; (void)n_in; (void)out_size;
    const float* embs = (const float*)d_in[0];
    const float* Wix = (const float*)d_in[1];  const float* bix = (const float*)d_in[2];
    const float* Wfx = (const float*)d_in[3];  const float* bfx = (const float*)d_in[4];
    const float* Wux = (const float*)d_in[5];  const float* bux = (const float*)d_in[6];
    const float* Wox = (const float*)d_in[7];  const float* box = (const float*)d_in[8];
    const float* Wih = (const float*)d_in[9];  const float* bih = (const float*)d_in[10];
    const float* Wfh = (const float*)d_in[11]; const float* bfh = (const float*)d_in[12];
    const float* Wuh = (const float*)d_in[13]; const float* buh = (const float*)d_in[14];
    const float* Woh = (const float*)d_in[15]; const float* boh = (const float*)d_in[16];
    float* out = (float*)d_out;

    char* p = (char*)d_ws;
    auto alloc = [&](size_t bytes) -> char* {
        char* r = p;
        p += (bytes + 255) & ~(size_t)255;
        return r;
    };
    unsigned short* PG   = (unsigned short*)alloc((size_t)NTOT * GW * 2);   // 111.8 MB
    float*          C    = (float*)alloc((size_t)NTOT * MEM * 4);           //  52.4 MB
    unsigned short* Hbf  = (unsigned short*)alloc((size_t)NTOT * KH * 2);   //  28.0 MB
    unsigned short* W4xT = (unsigned short*)alloc((size_t)GW * KXP * 2);
    unsigned short* W4hT = (unsigned short*)alloc((size_t)GW * KH * 2);
    unsigned short* WfhT = (unsigned short*)alloc((size_t)256 * KH * 2);
    unsigned short* W3hT = (unsigned short*)alloc((size_t)GW * KH * 2);
    float*          b4x  = (float*)alloc(GW * 4);
    float*          b4hf = (float*)alloc(GW * 4);
    float*          bfhb = (float*)alloc(256 * 4);
    float*          b3h  = (float*)alloc(GW * 4);
    if ((size_t)(p - (char*)d_ws) > ws_size) return;

    // Aliases in PG's dead leaf region (bytes [0, 84MB)): x-proj writes only
    // internal PG rows (>= 84MB) and leaf outputs go direct to out/C/Hbf.
    unsigned short* Abf = PG;                             // 55.9 MB (dead after xproj)
    unsigned short* Gf  = PG;                             // per-child f preacts, <= 21 MB
    unsigned short* Gc  = PG + (size_t)65536 * KH;        // tail scratch, <= 327 KB

    // ---- prep: pack weights + convert embs (1 dispatch) ----
    {
        int convBlocks = (NTOT * (KXP / 8) + 255) / 256;
        prep<<<256 + convBlocks, 256, 0, stream>>>(
            Wix, Wfx, Wux, Wox, bix, bfx, bux, box,
            Wih, Wfh, Wuh, Woh, bih, bfh, buh, boh, embs,
            W4xT, W4hT, WfhT, W3hT, b4x, b4hf, bfhb, b3h, Abf);
    }

    // ---- x-projections for ALL nodes; leaf cells fused in-epilogue ----
    {
        int mt = (NTOT + 127) / 128;
        gemm_lds<KXP, true><<<mt * 5, 256, 0, stream>>>(
            Abf, NTOT, W4xT, b4x, PG, GW, GW, 5, bih, buh, boh, out, C, Hbf);
    }

    // ---- levels d=1..4: f-GEMM + iuo-GEMM-with-fused-cell (2 dispatches) ----
    for (int d = 1; d <= 4; ++d) {
        int nprev = SIZES[d - 1];
        int n = SIZES[d];
        const unsigned short* Hprev = Hbf + (size_t)OFF[d - 1] * KH;
        int mtf = (nprev + 127) / 128;
        gemm_lds<KH, false><<<mtf * 2, 256, 0, stream>>>(
            Hprev, nprev, WfhT, bfhb, Gf, KH, KH, 2,
            nullptr, nullptr, nullptr, nullptr, nullptr, nullptr);
        int mt = (n + 127) / 128;
        gemm_iuo<<<mt * 5, 256, 0, stream>>>(
            Hprev, n, W3hT, b3h, Gf,
            PG + (size_t)OFF[d] * GW, C + (size_t)OFF[d - 1] * MEM,
            out + (size_t)OFF[d] * MEM, C + (size_t)OFF[d] * MEM,
            Hbf + (size_t)OFF[d] * KH);
    }

    // ---- tail levels d=5..8: one dispatch each ----
    for (int d = 5; d < DEPTH; ++d) {
        int nprev = SIZES[d - 1];
        int n = SIZES[d];
        tail_level<<<5, 256, 0, stream>>>(
            Hbf + (size_t)OFF[d - 1] * KH, nprev, n, W4hT, b4hf, Gc,
            PG + (size_t)OFF[d] * GW, C + (size_t)OFF[d - 1] * MEM,
            bih, buh, boh,
            out + (size_t)OFF[d] * MEM, C + (size_t)OFF[d] * MEM,
            Hbf + (size_t)OFF[d] * KH);
    }
}

// Round 5
// 440.722 us; speedup vs baseline: 1.0315x; 1.0315x over previous
//
#include <hip/hip_runtime.h>

#define IN_DIM 300
#define MEM    150
#define GP     160   // padded per-gate pitch
#define GW     640   // 4 gates * GP
#define KX     300   // x-proj real K
#define KXP    320   // x-proj padded K (bf16 A buffer pitch)
#define KH     160   // level GEMM K (padded, H buffer is pre-padded)
#define NLEAF  65536
#define NTOT   87381
#define DEPTH  9

static const int SIZES[DEPTH] = {65536,16384,4096,1024,256,64,16,4,1};
static const int OFF[DEPTH]   = {0,65536,81920,86016,87040,87296,87360,87376,87380};

typedef __attribute__((ext_vector_type(8))) short short8;
typedef __attribute__((ext_vector_type(4))) float f32x4;

__device__ __forceinline__ float sigf(float x) { return 1.0f / (1.0f + __expf(-x)); }
__device__ __forceinline__ float tanhf_fast(float x) {
    float e = __expf(2.0f * x);
    return 1.0f - 2.0f / (e + 1.0f);
}
__device__ __forceinline__ unsigned short f2bf(float f) {
    union { float f; unsigned u; } v; v.f = f;
    unsigned r = v.u + 0x7FFF + ((v.u >> 16) & 1);
    return (unsigned short)(r >> 16);
}
__device__ __forceinline__ float bf2f(unsigned short u) {
    union { unsigned u; float f; } v; v.u = ((unsigned)u) << 16; return v.f;
}

// async global->LDS, 16 bytes per lane
typedef const __attribute__((address_space(1))) unsigned int* as1_u32p;
typedef __attribute__((address_space(3))) unsigned int* as3_u32p;
__device__ __forceinline__ void gl_lds16(const unsigned short* g, unsigned short* l) {
    __builtin_amdgcn_global_load_lds((as1_u32p)g, (as3_u32p)l, 16, 0, 0);
}

// ---------------- weight packing: transposed bf16 weights + fp32 biases --------
__global__ void pack_weights(const float* __restrict__ Wix, const float* __restrict__ Wfx,
                             const float* __restrict__ Wux, const float* __restrict__ Wox,
                             const float* __restrict__ bix, const float* __restrict__ bfx,
                             const float* __restrict__ bux, const float* __restrict__ box,
                             const float* __restrict__ Wih, const float* __restrict__ Wfh,
                             const float* __restrict__ Wuh, const float* __restrict__ Woh,
                             const float* __restrict__ bfh,
                             unsigned short* __restrict__ W4xT, unsigned short* __restrict__ W4hT,
                             float* __restrict__ b4x, float* __restrict__ b4hf)
{
    int stride = gridDim.x * blockDim.x;
    int tid = blockIdx.x * blockDim.x + threadIdx.x;
    for (int idx = tid; idx < GW * KXP; idx += stride) {
        int c = idx / KXP, k = idx - c * KXP;
        int g = c / GP, j = c - g * GP;
        const float* W = (g == 0) ? Wix : (g == 1) ? Wfx : (g == 2) ? Wux : Wox;
        W4xT[idx] = (j < MEM && k < KX) ? f2bf(W[k * MEM + j]) : (unsigned short)0;
    }
    for (int idx = tid; idx < GW * KH; idx += stride) {
        int c = idx / KH, k = idx - c * KH;
        int g = c / GP, j = c - g * GP;
        const float* W = (g == 0) ? Wih : (g == 1) ? Wfh : (g == 2) ? Wuh : Woh;
        W4hT[idx] = (j < MEM && k < MEM) ? f2bf(W[k * MEM + j]) : (unsigned short)0;
    }
    for (int idx = tid; idx < GW; idx += stride) {
        int g = idx / GP, j = idx - g * GP;
        const float* b = (g == 0) ? bix : (g == 1) ? bfx : (g == 2) ? bux : box;
        b4x[idx]  = (j < MEM) ? b[j] : 0.0f;
        b4hf[idx] = (g == 1 && j < MEM) ? bfh[j] : 0.0f;
    }
}

// ---------------- embs fp32 -> bf16, padded to KXP cols ------------------------
__global__ void conv_embs(const float* __restrict__ embs, unsigned short* __restrict__ Abf)
{
    int idx = blockIdx.x * 256 + threadIdx.x;
    if (idx >= NTOT * (KXP / 8)) return;
    int n = idx / (KXP / 8), c = idx - n * (KXP / 8);
    int c0 = c * 8;
    unsigned short v[8];
    if (c0 + 8 <= KX) {
        const float4* p = (const float4*)(embs + (size_t)n * KX + c0);
        float4 f0 = p[0], f1 = p[1];
        v[0]=f2bf(f0.x); v[1]=f2bf(f0.y); v[2]=f2bf(f0.z); v[3]=f2bf(f0.w);
        v[4]=f2bf(f1.x); v[5]=f2bf(f1.y); v[6]=f2bf(f1.z); v[7]=f2bf(f1.w);
    } else {
        const float* row = embs + (size_t)n * KX;
        #pragma unroll
        for (int j = 0; j < 8; ++j) {
            int col = c0 + j;
            v[j] = (col < KX) ? f2bf(row[col]) : (unsigned short)0;
        }
    }
    *(short8*)&Abf[(size_t)n * KXP + c0] = *(short8*)v;
}

// ---------------- bf16 MFMA GEMM: 4-deep counted-vmcnt pipeline ----------------
// C[M x 640] = A[M x KPAD] @ BT^T + bias, Cout bf16 pitch GW.
// Tile 128x128, BK=32, FOUR LDS buffer sets, prefetch 3 stages ahead.
// Per K-stage: issue stage t+3 -> counted s_waitcnt vmcnt(12/8/4/0) (loads
// stay in flight across barriers; VMEM retires in-order so vmcnt(12) ==
// stage t landed) -> s_barrier -> sched_barrier(0) fence (rule #18: pin
// ds_reads after the wait) -> setprio(1) + 16 MFMA -> s_barrier.
// LDS layout linear (required by global_load_lds); k-chunk XOR swizzle on
// BOTH global source addr and ds_read addr (rule #21).
template<int KPAD>
__global__ __launch_bounds__(256) void gemm_lds(
    const unsigned short* __restrict__ A, int M,
    const unsigned short* __restrict__ BT,
    const float* __restrict__ bias,
    unsigned short* __restrict__ Cout)
{
    __shared__ __align__(16) unsigned short As[4][4096];
    __shared__ __align__(16) unsigned short Bs[4][4096];

    // bijective XCD swizzle (m204)
    const int nwg = gridDim.x;
    const int orig = blockIdx.x;
    const int qq = nwg >> 3, rr = nwg & 7;
    const int xcd = orig & 7, lin = orig >> 3;
    const int dd = (xcd < rr ? xcd * (qq + 1) : rr * (qq + 1) + (xcd - rr) * qq) + lin;
    const int mtile = dd / 5, ntile = dd - mtile * 5;

    const int t = threadIdx.x;
    const int m0 = mtile * 128, n0 = ntile * 128;
    const int l = t & 63, w = t >> 6;
    const int l15 = l & 15, q = l >> 4;
    const int wm = (w & 1) * 64, wn = (w >> 1) * 64;

    // staging: thread t covers LDS 16B chunk at elem t*8 (rows 0..63) and
    // 2048 + t*8 (rows 64..127). row = t>>2, k-chunk = t&3, source k-chunk
    // XOR-swizzled by (row&3).
    const int srow = t >> 2;
    const int scol = ((t & 3) ^ (srow & 3)) * 8;   // elems
    int gr0 = m0 + srow;      if (gr0 >= M) gr0 = M - 1;
    int gr1 = m0 + 64 + srow; if (gr1 >= M) gr1 = M - 1;
    const unsigned short* a0 = A + (size_t)gr0 * KPAD + scol;
    const unsigned short* a1 = A + (size_t)gr1 * KPAD + scol;
    const unsigned short* b0 = BT + (size_t)(n0 + srow) * KPAD + scol;
    const unsigned short* b1 = BT + (size_t)(n0 + 64 + srow) * KPAD + scol;

    f32x4 acc[4][4];
    #pragma unroll
    for (int i = 0; i < 4; ++i)
        #pragma unroll
        for (int j = 0; j < 4; ++j)
            acc[i][j] = (f32x4){0.f, 0.f, 0.f, 0.f};

    auto issue = [&](int s) {
        const int ko = s << 5;
        const int b = s & 3;
        gl_lds16(a0 + ko, &As[b][t * 8]);
        gl_lds16(a1 + ko, &As[b][2048 + t * 8]);
        gl_lds16(b0 + ko, &Bs[b][t * 8]);
        gl_lds16(b1 + ko, &Bs[b][2048 + t * 8]);
    };

    const int NST = KPAD >> 5;                // 10 (x-proj) or 5 (levels)
    issue(0); issue(1); issue(2);             // 3-deep prologue (12 loads)

    #pragma unroll
    for (int kt = 0; kt < NST; ++kt) {
        if (kt + 3 < NST) issue(kt + 3);
        __builtin_amdgcn_sched_barrier(0);    // pin issue before the wait
        const int rem = NST - 1 - kt;
        if (rem >= 3)      asm volatile("s_waitcnt vmcnt(12)" ::: "memory");
        else if (rem == 2) asm volatile("s_waitcnt vmcnt(8)" ::: "memory");
        else if (rem == 1) asm volatile("s_waitcnt vmcnt(4)" ::: "memory");
        else               asm volatile("s_waitcnt vmcnt(0)" ::: "memory");
        __builtin_amdgcn_s_barrier();         // all waves' stage-kt DMA landed
        __builtin_amdgcn_sched_barrier(0);    // rule #18: no ds_read hoisting

        const unsigned short* Ab = As[kt & 3];
        const unsigned short* Bb = Bs[kt & 3];
        short8 a[4], b[4];
        const int csw = (q ^ (l15 & 3)) * 8;  // de-swizzled k-chunk
        #pragma unroll
        for (int i = 0; i < 4; ++i)
            a[i] = *(const short8*)&Ab[(wm + i * 16 + l15) * 32 + csw];
        #pragma unroll
        for (int j = 0; j < 4; ++j)
            b[j] = *(const short8*)&Bb[(wn + j * 16 + l15) * 32 + csw];
        __builtin_amdgcn_s_setprio(1);
        #pragma unroll
        for (int i = 0; i < 4; ++i)
            #pragma unroll
            for (int j = 0; j < 4; ++j)
                acc[i][j] = __builtin_amdgcn_mfma_f32_16x16x32_bf16(a[i], b[j], acc[i][j], 0, 0, 0);
        __builtin_amdgcn_s_setprio(0);
        __builtin_amdgcn_sched_barrier(0);    // keep reads/MFMA inside the phase
        __builtin_amdgcn_s_barrier();         // retire reads before buf reuse
    }

    // ---- epilogue: bias + bf16 store. C/D: row = q*4+reg, col = lane&15 ----
    float bj[4];
    #pragma unroll
    for (int j = 0; j < 4; ++j) bj[j] = bias[n0 + wn + j * 16 + l15];
    #pragma unroll
    for (int i = 0; i < 4; ++i) {
        #pragma unroll
        for (int r = 0; r < 4; ++r) {
            int grow = m0 + wm + i * 16 + q * 4 + r;
            if (grow < M) {
                unsigned short* crow = Cout + (size_t)grow * GW;
                #pragma unroll
                for (int j = 0; j < 4; ++j)
                    crow[n0 + wn + j * 16 + l15] = f2bf(acc[i][j][r] + bj[j]);
            }
        }
    }
}

// ---------------- leaf elementwise: gates i,u,o -> c,h,Hbf ---------------------
__global__ void leaf_ew(const unsigned short* __restrict__ PG,
                        const float* __restrict__ bih, const float* __restrict__ buh,
                        const float* __restrict__ boh,
                        float* __restrict__ out, float* __restrict__ C,
                        unsigned short* __restrict__ Hbf)
{
    int idx = blockIdx.x * 256 + threadIdx.x;
    if (idx >= NLEAF * MEM) return;
    int n = idx / MEM, m = idx - n * MEM;
    const unsigned short* row = PG + (size_t)n * GW;
    float ip = bf2f(row[m])          + bih[m];
    float up = bf2f(row[2 * GP + m]) + buh[m];
    float op = bf2f(row[3 * GP + m]) + boh[m];
    float i = sigf(ip), u = tanhf_fast(up), o = sigf(op);
    float c = i * u;
    float h = o * tanhf_fast(c);
    out[idx] = h;
    C[idx] = c;
    Hbf[(size_t)n * KH + m] = f2bf(h);
    if (m < KH - MEM) Hbf[(size_t)n * KH + MEM + m] = 0;   // zero pad cols
}

// ---------------- internal-level elementwise ------------------------------------
__global__ void level_ew(const unsigned short* __restrict__ G,
                         const unsigned short* __restrict__ P,
                         const float* __restrict__ Cprev,
                         const float* __restrict__ bih, const float* __restrict__ buh,
                         const float* __restrict__ boh,
                         float* __restrict__ outRow, float* __restrict__ Crow,
                         unsigned short* __restrict__ HbfRow, int n)
{
    int idx = blockIdx.x * 256 + threadIdx.x;
    if (idx >= n * MEM) return;
    int nn = idx / MEM, m = idx - nn * MEM;
    const unsigned short* xr = P + (size_t)nn * GW;
    float ip = bf2f(xr[m]) + bih[m];
    float fx = bf2f(xr[GP + m]);           // x@W_fx + b_fx
    float up = bf2f(xr[2 * GP + m]) + buh[m];
    float op = bf2f(xr[3 * GP + m]) + boh[m];
    float fc = 0.0f;
    #pragma unroll
    for (int k = 0; k < 4; ++k) {
        const unsigned short* gr = G + (size_t)(4 * nn + k) * GW;
        ip += bf2f(gr[m]);
        up += bf2f(gr[2 * GP + m]);
        op += bf2f(gr[3 * GP + m]);
        float f = sigf(fx + bf2f(gr[GP + m]));  // + (h_k@W_fh + b_fh)
        fc += f * Cprev[(4 * nn + k) * MEM + m];
    }
    float i = sigf(ip), u = tanhf_fast(up), o = sigf(op);
    float c = i * u + fc;
    float h = o * tanhf_fast(c);
    outRow[idx] = h;
    Crow[idx] = c;
    HbfRow[(size_t)nn * KH + m] = f2bf(h);
    if (m < KH - MEM) HbfRow[(size_t)nn * KH + MEM + m] = 0;
}

extern "C" void kernel_launch(void* const* d_in, const int* in_sizes, int n_in,
                              void* d_out, int out_size, void* d_ws, size_t ws_size,
                              hipStream_t stream)
{
    (void)in_sizes; (void)n_in; (void)out_size;
    const float* embs = (const float*)d_in[0];
    const float* Wix = (const float*)d_in[1];  const float* bix = (const float*)d_in[2];
    const float* Wfx = (const float*)d_in[3];  const float* bfx = (const float*)d_in[4];
    const float* Wux = (const float*)d_in[5];  const float* bux = (const float*)d_in[6];
    const float* Wox = (const float*)d_in[7];  const float* box = (const float*)d_in[8];
    const float* Wih = (const float*)d_in[9];  const float* bih = (const float*)d_in[10];
    const float* Wfh = (const float*)d_in[11]; const float* bfh = (const float*)d_in[12];
    const float* Wuh = (const float*)d_in[13]; const float* buh = (const float*)d_in[14];
    const float* Woh = (const float*)d_in[15]; const float* boh = (const float*)d_in[16];
    float* out = (float*)d_out;

    char* p = (char*)d_ws;
    auto alloc = [&](size_t bytes) -> char* {
        char* r = p;
        p += (bytes + 255) & ~(size_t)255;
        return r;
    };
    unsigned short* PG   = (unsigned short*)alloc((size_t)NTOT * GW * 2);
    float*          C    = (float*)alloc((size_t)NTOT * MEM * 4);
    unsigned short* Hbf  = (unsigned short*)alloc((size_t)NTOT * KH * 2);
    unsigned short* W4xT = (unsigned short*)alloc((size_t)GW * KXP * 2);
    unsigned short* W4hT = (unsigned short*)alloc((size_t)GW * KH * 2);
    float*          b4x  = (float*)alloc(GW * 4);
    float*          b4hf = (float*)alloc(GW * 4);
    if ((size_t)(p - (char*)d_ws) > ws_size) return;  // ws too small: bail

    // Abf (bf16 embs, NTOT x KXP = 55.9 MB) ALIASES the C+Hbf region (80.4 MB):
    // its last read (x-proj GEMM) strictly precedes the first write of C/Hbf
    // (leaf_ew) in stream order.
    unsigned short* Abf = (unsigned short*)C;

    pack_weights<<<128, 256, 0, stream>>>(Wix, Wfx, Wux, Wox, bix, bfx, bux, box,
                                          Wih, Wfh, Wuh, Woh, bfh,
                                          W4xT, W4hT, b4x, b4hf);

    // fp32 -> bf16 conversion of all node embeddings (padded K)
    conv_embs<<<(NTOT * (KXP / 8) + 255) / 256, 256, 0, stream>>>(embs, Abf);

    // x-projections for ALL nodes (row = global node id), bf16 out
    {
        int mt = (NTOT + 127) / 128;
        gemm_lds<KXP><<<mt * 5, 256, 0, stream>>>(Abf, NTOT, W4xT, b4x, PG);
    }

    // leaves
    leaf_ew<<<(NLEAF * MEM + 255) / 256, 256, 0, stream>>>(PG, bih, buh, boh, out, C, Hbf);

    // internal levels (sequential)
    for (int d = 1; d < DEPTH; ++d) {
        int nprev = SIZES[d - 1];
        int n = SIZES[d];
        int mt = (nprev + 127) / 128;
        // G = H_prev @ W4h (+ b_fh on f gate), overwrites PG rows [0, nprev) —
        // always strictly below this level's x-proj rows (OFF[d] >= 65536).
        gemm_lds<KH><<<mt * 5, 256, 0, stream>>>(
            Hbf + (size_t)OFF[d - 1] * KH, nprev, W4hT, b4hf, PG);
        level_ew<<<(n * MEM + 255) / 256, 256, 0, stream>>>(
            PG, PG + (size_t)OFF[d] * GW,
            C + (size_t)OFF[d - 1] * MEM,
            bih, buh, boh,
            out + (size_t)OFF[d] * MEM, C + (size_t)OFF[d] * MEM,
            Hbf + (size_t)OFF[d] * KH, n);
    }
}

// Round 6
// 371.789 us; speedup vs baseline: 1.2227x; 1.1854x over previous
//
#include <hip/hip_runtime.h>

#define MEM    150
#define GW     640   // 4 gates interleaved: col = 4*j + g  (g: 0=i,1=f,2=u,3=o)
#define KX     300   // x-proj real K
#define KXP    320   // x-proj padded K (bf16 A buffer pitch)
#define KH     160   // level GEMM K (padded, H buffer is pre-padded)
#define NLEAF  65536
#define NTOT   87381
#define DEPTH  9

static const int SIZES[DEPTH] = {65536,16384,4096,1024,256,64,16,4,1};
static const int OFF[DEPTH]   = {0,65536,81920,86016,87040,87296,87360,87376,87380};

typedef __attribute__((ext_vector_type(8))) short short8;
typedef __attribute__((ext_vector_type(4))) float f32x4;

__device__ __forceinline__ float sigf(float x) { return 1.0f / (1.0f + __expf(-x)); }
__device__ __forceinline__ float tanhf_fast(float x) {
    float e = __expf(2.0f * x);
    return 1.0f - 2.0f / (e + 1.0f);
}
__device__ __forceinline__ unsigned short f2bf(float f) {
    union { float f; unsigned u; } v; v.f = f;
    unsigned r = v.u + 0x7FFF + ((v.u >> 16) & 1);
    return (unsigned short)(r >> 16);
}
__device__ __forceinline__ float bf2f(unsigned short u) {
    union { unsigned u; float f; } v; v.u = ((unsigned)u) << 16; return v.f;
}

// async global->LDS, 16 bytes per lane
typedef const __attribute__((address_space(1))) unsigned int* as1_u32p;
typedef __attribute__((address_space(3))) unsigned int* as3_u32p;
__device__ __forceinline__ void gl_lds16(const unsigned short* g, unsigned short* l) {
    __builtin_amdgcn_global_load_lds((as1_u32p)g, (as3_u32p)l, 16, 0, 0);
}

// ---------------- weight packing: interleaved transposed bf16 + fp32 biases ----
// W4xT: 640 x KXP, row c=4j+g from W_gx[k][j]
// W4hT: 640 x KH,  row c=4j+g from W_gh[k][j]
// b4x[4j+g] = b_gx[j]; b4hf[4j+g] = (g==1) ? bfh[j] : 0
__global__ void pack_weights(const float* __restrict__ Wix, const float* __restrict__ Wfx,
                             const float* __restrict__ Wux, const float* __restrict__ Wox,
                             const float* __restrict__ bix, const float* __restrict__ bfx,
                             const float* __restrict__ bux, const float* __restrict__ box,
                             const float* __restrict__ Wih, const float* __restrict__ Wfh,
                             const float* __restrict__ Wuh, const float* __restrict__ Woh,
                             const float* __restrict__ bfh,
                             unsigned short* __restrict__ W4xT, unsigned short* __restrict__ W4hT,
                             float* __restrict__ b4x, float* __restrict__ b4hf)
{
    int stride = gridDim.x * blockDim.x;
    int tid = blockIdx.x * blockDim.x + threadIdx.x;
    for (int idx = tid; idx < GW * KXP; idx += stride) {
        int c = idx / KXP, k = idx - c * KXP;
        int j = c >> 2, g = c & 3;
        const float* W = (g == 0) ? Wix : (g == 1) ? Wfx : (g == 2) ? Wux : Wox;
        W4xT[idx] = (j < MEM && k < KX) ? f2bf(W[k * MEM + j]) : (unsigned short)0;
    }
    for (int idx = tid; idx < GW * KH; idx += stride) {
        int c = idx / KH, k = idx - c * KH;
        int j = c >> 2, g = c & 3;
        const float* W = (g == 0) ? Wih : (g == 1) ? Wfh : (g == 2) ? Wuh : Woh;
        W4hT[idx] = (j < MEM && k < MEM) ? f2bf(W[k * MEM + j]) : (unsigned short)0;
    }
    for (int idx = tid; idx < GW; idx += stride) {
        int j = idx >> 2, g = idx & 3;
        const float* b = (g == 0) ? bix : (g == 1) ? bfx : (g == 2) ? bux : box;
        b4x[idx]  = (j < MEM) ? b[j] : 0.0f;
        b4hf[idx] = (g == 1 && j < MEM) ? bfh[j] : 0.0f;
    }
}

// ---------------- embs fp32 -> bf16, padded to KXP cols ------------------------
__global__ void conv_embs(const float* __restrict__ embs, unsigned short* __restrict__ Abf)
{
    int idx = blockIdx.x * 256 + threadIdx.x;
    if (idx >= NTOT * (KXP / 8)) return;
    int n = idx / (KXP / 8), c = idx - n * (KXP / 8);
    int c0 = c * 8;
    unsigned short v[8];
    if (c0 + 8 <= KX) {
        const float4* p = (const float4*)(embs + (size_t)n * KX + c0);
        float4 f0 = p[0], f1 = p[1];
        v[0]=f2bf(f0.x); v[1]=f2bf(f0.y); v[2]=f2bf(f0.z); v[3]=f2bf(f0.w);
        v[4]=f2bf(f1.x); v[5]=f2bf(f1.y); v[6]=f2bf(f1.z); v[7]=f2bf(f1.w);
    } else {
        const float* row = embs + (size_t)n * KX;
        #pragma unroll
        for (int j = 0; j < 8; ++j) {
            int col = c0 + j;
            v[j] = (col < KX) ? f2bf(row[col]) : (unsigned short)0;
        }
    }
    *(short8*)&Abf[(size_t)n * KXP + c0] = *(short8*)v;
}

// ---------------- x-proj GEMM (R1 core) + leaf-cell fused epilogue -------------
// C[M x 640] = A @ W4xT^T + b4x. Tile 128x128, BK=32, 2-buffer, one barrier
// pair per K-step (the measured-best core). Epilogue goes through a 32KB LDS
// transpose tile: leaf tiles (m0 < NLEAF) compute the LSTM cell in-kernel and
// write out/C/Hbf directly; internal tiles write bf16 PG rows (pitch GW).
__global__ __launch_bounds__(256) void gemm_xproj(
    const unsigned short* __restrict__ A,
    const unsigned short* __restrict__ BT,
    const float* __restrict__ bias,
    unsigned short* __restrict__ PG,
    const float* __restrict__ bih, const float* __restrict__ buh,
    const float* __restrict__ boh,
    float* __restrict__ outLeaf, float* __restrict__ CLeaf,
    unsigned short* __restrict__ HbfLeaf)
{
    __shared__ __align__(16) unsigned short lds[16384];   // As[2]|Bs[2] / epi tile
    unsigned short* As = lds;          // [2][4096]
    unsigned short* Bs = lds + 8192;   // [2][4096]

    // bijective XCD swizzle (m204)
    const int nwg = gridDim.x;
    const int orig = blockIdx.x;
    const int qq = nwg >> 3, rr = nwg & 7;
    const int xcd = orig & 7, lin = orig >> 3;
    const int dd = (xcd < rr ? xcd * (qq + 1) : rr * (qq + 1) + (xcd - rr) * qq) + lin;
    const int mtile = dd / 5, ntile = dd - mtile * 5;

    const int t = threadIdx.x;
    const int m0 = mtile * 128, n0 = ntile * 128;
    const int l = t & 63, w = t >> 6;
    const int l15 = l & 15, q = l >> 4;
    const int wm = (w & 1) * 64, wn = (w >> 1) * 64;

    const int srow = t >> 2;
    const int scol = ((t & 3) ^ (srow & 3)) * 8;   // k-chunk XOR swizzle (rule #21)
    int gr0 = m0 + srow;      if (gr0 >= NTOT) gr0 = NTOT - 1;
    int gr1 = m0 + 64 + srow; if (gr1 >= NTOT) gr1 = NTOT - 1;
    const unsigned short* a0 = A + (size_t)gr0 * KXP + scol;
    const unsigned short* a1 = A + (size_t)gr1 * KXP + scol;
    const unsigned short* b0 = BT + (size_t)(n0 + srow) * KXP + scol;
    const unsigned short* b1 = BT + (size_t)(n0 + 64 + srow) * KXP + scol;

    f32x4 acc[4][4];
    #pragma unroll
    for (int i = 0; i < 4; ++i)
        #pragma unroll
        for (int j = 0; j < 4; ++j)
            acc[i][j] = (f32x4){0.f, 0.f, 0.f, 0.f};

    gl_lds16(a0, As + t * 8);
    gl_lds16(a1, As + 2048 + t * 8);
    gl_lds16(b0, Bs + t * 8);
    gl_lds16(b1, Bs + 2048 + t * 8);
    __syncthreads();

    int cur = 0;
    const int kiters = KXP >> 5;   // 10
    for (int kt = 0; kt < kiters; ++kt) {
        if (kt + 1 < kiters) {
            const int ko = (kt + 1) << 5;
            const int nb = cur ^ 1;
            gl_lds16(a0 + ko, As + nb * 4096 + t * 8);
            gl_lds16(a1 + ko, As + nb * 4096 + 2048 + t * 8);
            gl_lds16(b0 + ko, Bs + nb * 4096 + t * 8);
            gl_lds16(b1 + ko, Bs + nb * 4096 + 2048 + t * 8);
        }
        short8 a[4], b[4];
        const int csw = (q ^ (l15 & 3)) * 8;
        #pragma unroll
        for (int i = 0; i < 4; ++i)
            a[i] = *(const short8*)&As[cur * 4096 + (wm + i * 16 + l15) * 32 + csw];
        #pragma unroll
        for (int j = 0; j < 4; ++j)
            b[j] = *(const short8*)&Bs[cur * 4096 + (wn + j * 16 + l15) * 32 + csw];
        #pragma unroll
        for (int i = 0; i < 4; ++i)
            #pragma unroll
            for (int j = 0; j < 4; ++j)
                acc[i][j] = __builtin_amdgcn_mfma_f32_16x16x32_bf16(a[i], b[j], acc[i][j], 0, 0, 0);
        __syncthreads();
        cur ^= 1;
    }

    // ---- epilogue: bias + bf16 into LDS tile [128][128] ----
    float bj[4];
    #pragma unroll
    for (int j = 0; j < 4; ++j) bj[j] = bias[n0 + wn + j * 16 + l15];
    #pragma unroll
    for (int i = 0; i < 4; ++i)
        #pragma unroll
        for (int j = 0; j < 4; ++j)
            #pragma unroll
            for (int r = 0; r < 4; ++r)
                lds[(wm + i * 16 + q * 4 + r) * 128 + wn + j * 16 + l15] =
                    f2bf(acc[i][j][r] + bj[j]);
    __syncthreads();

    if (m0 < NLEAF) {
        // leaf LSTM cell: tile holds cols 4*j+g for j in [32*ntile, +32)
        #pragma unroll
        for (int s = 0; s < 16; ++s) {
            int idx = (s << 8) + t;
            int row = idx >> 5, jl = idx & 31;
            int grow = m0 + row;
            int j = ntile * 32 + jl;
            const unsigned short* g4 = &lds[row * 128 + jl * 4];
            if (j < MEM) {
                float gi = bf2f(g4[0]) + bih[j];
                float gu = bf2f(g4[2]) + buh[j];
                float go = bf2f(g4[3]) + boh[j];
                float iv = sigf(gi), uv = tanhf_fast(gu), ov = sigf(go);
                float c = iv * uv;
                float h = ov * tanhf_fast(c);
                outLeaf[(size_t)grow * MEM + j] = h;
                CLeaf[(size_t)grow * MEM + j] = c;
                HbfLeaf[(size_t)grow * KH + j] = f2bf(h);
            } else if (j < KH) {
                HbfLeaf[(size_t)grow * KH + j] = 0;
            }
        }
    } else {
        int row = t >> 1, half = t & 1;
        int grow = m0 + row;
        if (grow < NTOT) {
            const unsigned short* src = &lds[row * 128 + half * 64];
            unsigned short* dst = PG + (size_t)grow * GW + n0 + half * 64;
            #pragma unroll
            for (int c8 = 0; c8 < 8; ++c8)
                *(short8*)(dst + c8 * 8) = *(const short8*)(src + c8 * 8);
        }
    }
}

// ---------------- level GEMM + fully-fused cell epilogue -----------------------
// A = Hprev (nprev child rows, pitch KH); B = W4hT interleaved; b4hf = f-bias.
// A 128x128 tile holds the 4-gate preacts of 128 children = 32 parents for
// this N-tile's 32 features -> the cell computes in-epilogue. No G round-trip,
// no separate level_ew dispatch.
__global__ __launch_bounds__(256) void gemm_level(
    const unsigned short* __restrict__ Hprev, int nprev, int npar,
    const unsigned short* __restrict__ BT, const float* __restrict__ bias,
    const unsigned short* __restrict__ P,     // this level's x-proj rows
    const float* __restrict__ Cprev,
    const float* __restrict__ bih, const float* __restrict__ buh,
    const float* __restrict__ boh,
    float* __restrict__ outRow, float* __restrict__ Crow,
    unsigned short* __restrict__ HbfRow)
{
    __shared__ __align__(16) unsigned short lds[16384];
    unsigned short* As = lds;
    unsigned short* Bs = lds + 8192;

    const int nwg = gridDim.x;
    const int orig = blockIdx.x;
    const int qq = nwg >> 3, rr = nwg & 7;
    const int xcd = orig & 7, lin = orig >> 3;
    const int dd = (xcd < rr ? xcd * (qq + 1) : rr * (qq + 1) + (xcd - rr) * qq) + lin;
    const int mtile = dd / 5, ntile = dd - mtile * 5;

    const int t = threadIdx.x;
    const int m0 = mtile * 128, n0 = ntile * 128;
    const int l = t & 63, w = t >> 6;
    const int l15 = l & 15, q = l >> 4;
    const int wm = (w & 1) * 64, wn = (w >> 1) * 64;

    const int srow = t >> 2;
    const int scol = ((t & 3) ^ (srow & 3)) * 8;
    int gr0 = m0 + srow;      if (gr0 >= nprev) gr0 = nprev - 1;
    int gr1 = m0 + 64 + srow; if (gr1 >= nprev) gr1 = nprev - 1;
    const unsigned short* a0 = Hprev + (size_t)gr0 * KH + scol;
    const unsigned short* a1 = Hprev + (size_t)gr1 * KH + scol;
    const unsigned short* b0 = BT + (size_t)(n0 + srow) * KH + scol;
    const unsigned short* b1 = BT + (size_t)(n0 + 64 + srow) * KH + scol;

    f32x4 acc[4][4];
    #pragma unroll
    for (int i = 0; i < 4; ++i)
        #pragma unroll
        for (int j = 0; j < 4; ++j)
            acc[i][j] = (f32x4){0.f, 0.f, 0.f, 0.f};

    gl_lds16(a0, As + t * 8);
    gl_lds16(a1, As + 2048 + t * 8);
    gl_lds16(b0, Bs + t * 8);
    gl_lds16(b1, Bs + 2048 + t * 8);
    __syncthreads();

    int cur = 0;
    const int kiters = KH >> 5;   // 5
    for (int kt = 0; kt < kiters; ++kt) {
        if (kt + 1 < kiters) {
            const int ko = (kt + 1) << 5;
            const int nb = cur ^ 1;
            gl_lds16(a0 + ko, As + nb * 4096 + t * 8);
            gl_lds16(a1 + ko, As + nb * 4096 + 2048 + t * 8);
            gl_lds16(b0 + ko, Bs + nb * 4096 + t * 8);
            gl_lds16(b1 + ko, Bs + nb * 4096 + 2048 + t * 8);
        }
        short8 a[4], b[4];
        const int csw = (q ^ (l15 & 3)) * 8;
        #pragma unroll
        for (int i = 0; i < 4; ++i)
            a[i] = *(const short8*)&As[cur * 4096 + (wm + i * 16 + l15) * 32 + csw];
        #pragma unroll
        for (int j = 0; j < 4; ++j)
            b[j] = *(const short8*)&Bs[cur * 4096 + (wn + j * 16 + l15) * 32 + csw];
        #pragma unroll
        for (int i = 0; i < 4; ++i)
            #pragma unroll
            for (int j = 0; j < 4; ++j)
                acc[i][j] = __builtin_amdgcn_mfma_f32_16x16x32_bf16(a[i], b[j], acc[i][j], 0, 0, 0);
        __syncthreads();
        cur ^= 1;
    }

    // ---- per-child preacts (bf16, f-bias applied) into LDS tile [128][128] ----
    float bj[4];
    #pragma unroll
    for (int j = 0; j < 4; ++j) bj[j] = bias[n0 + wn + j * 16 + l15];
    #pragma unroll
    for (int i = 0; i < 4; ++i)
        #pragma unroll
        for (int j = 0; j < 4; ++j)
            #pragma unroll
            for (int r = 0; r < 4; ++r)
                lds[(wm + i * 16 + q * 4 + r) * 128 + wn + j * 16 + l15] =
                    f2bf(acc[i][j][r] + bj[j]);
    __syncthreads();

    // ---- fused cell: 32 parents x 32 features per block ----
    const int pp0 = m0 >> 2;
    #pragma unroll
    for (int s = 0; s < 4; ++s) {
        int idx = (s << 8) + t;          // 0..1023
        int pl = idx >> 5, jl = idx & 31;
        int par = pp0 + pl;
        if (par >= npar) continue;
        int j = ntile * 32 + jl;
        if (j < MEM) {
            const unsigned short* xr = P + (size_t)par * GW + 4 * j;
            float ip = bf2f(xr[0]) + bih[j];
            float fx = bf2f(xr[1]);
            float up = bf2f(xr[2]) + buh[j];
            float op = bf2f(xr[3]) + boh[j];
            float fc = 0.0f;
            #pragma unroll
            for (int k = 0; k < 4; ++k) {
                const unsigned short* g4 = &lds[(pl * 4 + k) * 128 + jl * 4];
                ip += bf2f(g4[0]);
                up += bf2f(g4[2]);
                op += bf2f(g4[3]);
                float f = sigf(fx + bf2f(g4[1]));
                fc += f * Cprev[(size_t)(4 * par + k) * MEM + j];
            }
            float iv = sigf(ip), uv = tanhf_fast(up), ov = sigf(op);
            float c = iv * uv + fc;
            float h = ov * tanhf_fast(c);
            outRow[(size_t)par * MEM + j] = h;
            Crow[(size_t)par * MEM + j] = c;
            HbfRow[(size_t)par * KH + j] = f2bf(h);
        } else if (j < KH) {
            HbfRow[(size_t)par * KH + j] = 0;
        }
    }
}

extern "C" void kernel_launch(void* const* d_in, const int* in_sizes, int n_in,
                              void* d_out, int out_size, void* d_ws, size_t ws_size,
                              hipStream_t stream)
{
    (void)in_sizes; (void)n_in; (void)out_size;
    const float* embs = (const float*)d_in[0];
    const float* Wix = (const float*)d_in[1];  const float* bix = (const float*)d_in[2];
    const float* Wfx = (const float*)d_in[3];  const float* bfx = (const float*)d_in[4];
    const float* Wux = (const float*)d_in[5];  const float* bux = (const float*)d_in[6];
    const float* Wox = (const float*)d_in[7];  const float* box = (const float*)d_in[8];
    const float* Wih = (const float*)d_in[9];  const float* bih = (const float*)d_in[10];
    const float* Wfh = (const float*)d_in[11]; const float* bfh = (const float*)d_in[12];
    const float* Wuh = (const float*)d_in[13]; const float* buh = (const float*)d_in[14];
    const float* Woh = (const float*)d_in[15]; const float* boh = (const float*)d_in[16];
    float* out = (float*)d_out;

    char* p = (char*)d_ws;
    auto alloc = [&](size_t bytes) -> char* {
        char* r = p;
        p += (bytes + 255) & ~(size_t)255;
        return r;
    };
    unsigned short* PG   = (unsigned short*)alloc((size_t)NTOT * GW * 2);   // 111.8 MB
    float*          C    = (float*)alloc((size_t)NTOT * MEM * 4);           //  52.4 MB
    unsigned short* Hbf  = (unsigned short*)alloc((size_t)NTOT * KH * 2);   //  28.0 MB
    unsigned short* W4xT = (unsigned short*)alloc((size_t)GW * KXP * 2);
    unsigned short* W4hT = (unsigned short*)alloc((size_t)GW * KH * 2);
    float*          b4x  = (float*)alloc(GW * 4);
    float*          b4hf = (float*)alloc(GW * 4);
    if ((size_t)(p - (char*)d_ws) > ws_size) return;

    // Abf (bf16 embs, NTOT*KXP = 55.9 MB) aliases PG's LEAF region (bytes
    // [0, 83.9 MB)): the x-proj GEMM reads Abf while writing only internal PG
    // rows (byte offset >= NLEAF*GW*2 = 83.9 MB); leaf cells go direct to
    // out/C/Hbf. The leaf PG region is otherwise dead.
    unsigned short* Abf = PG;

    pack_weights<<<128, 256, 0, stream>>>(Wix, Wfx, Wux, Wox, bix, bfx, bux, box,
                                          Wih, Wfh, Wuh, Woh, bfh,
                                          W4xT, W4hT, b4x, b4hf);

    conv_embs<<<(NTOT * (KXP / 8) + 255) / 256, 256, 0, stream>>>(embs, Abf);

    // x-projections for ALL nodes; leaf cells fused in-epilogue
    {
        int mt = (NTOT + 127) / 128;
        gemm_xproj<<<mt * 5, 256, 0, stream>>>(
            Abf, W4xT, b4x, PG, bih, buh, boh, out, C, Hbf);
    }

    // levels: one fused GEMM+cell dispatch each
    for (int d = 1; d < DEPTH; ++d) {
        int nprev = SIZES[d - 1];
        int n = SIZES[d];
        int mt = (nprev + 127) / 128;
        gemm_level<<<mt * 5, 256, 0, stream>>>(
            Hbf + (size_t)OFF[d - 1] * KH, nprev, n,
            W4hT, b4hf,
            PG + (size_t)OFF[d] * GW,
            C + (size_t)OFF[d - 1] * MEM,
            bih, buh, boh,
            out + (size_t)OFF[d] * MEM, C + (size_t)OFF[d] * MEM,
            Hbf + (size_t)OFF[d] * KH);
    }
}

// Round 7
// 349.858 us; speedup vs baseline: 1.2994x; 1.0627x over previous
//
#include <hip/hip_runtime.h>

#define MEM    150
#define GW     640   // 4 gates interleaved: col = 4*j + g  (g: 0=i,1=f,2=u,3=o)
#define KX     300   // x-proj real K
#define KXP    320   // x-proj padded K (bf16 A buffer pitch)
#define KH     160   // level GEMM K (padded, H buffer is pre-padded)
#define NLEAF  65536
#define NTOT   87381
#define DEPTH  9

static const int SIZES[DEPTH] = {65536,16384,4096,1024,256,64,16,4,1};
static const int OFF[DEPTH]   = {0,65536,81920,86016,87040,87296,87360,87376,87380};

typedef __attribute__((ext_vector_type(8))) short short8;
typedef __attribute__((ext_vector_type(4))) float f32x4;

__device__ __forceinline__ float sigf(float x) { return 1.0f / (1.0f + __expf(-x)); }
__device__ __forceinline__ float tanhf_fast(float x) {
    float e = __expf(2.0f * x);
    return 1.0f - 2.0f / (e + 1.0f);
}
__device__ __forceinline__ unsigned short f2bf(float f) {
    union { float f; unsigned u; } v; v.f = f;
    unsigned r = v.u + 0x7FFF + ((v.u >> 16) & 1);
    return (unsigned short)(r >> 16);
}
__device__ __forceinline__ float bf2f(unsigned short u) {
    union { unsigned u; float f; } v; v.u = ((unsigned)u) << 16; return v.f;
}

// async global->LDS, 16 bytes per lane
typedef const __attribute__((address_space(1))) unsigned int* as1_u32p;
typedef __attribute__((address_space(3))) unsigned int* as3_u32p;
__device__ __forceinline__ void gl_lds16(const unsigned short* g, unsigned short* l) {
    __builtin_amdgcn_global_load_lds((as1_u32p)g, (as3_u32p)l, 16, 0, 0);
}

// ---------------- prep: weight packing + embs conversion (one dispatch) --------
// W4xT: 640 x KXP, row c=4j+g from W_gx[k][j]; W4hT: 640 x KH same layout.
// b4x[4j+g]=b_gx[j]; b4hf[4j+g]=(g==1)?bfh[j]:0. Abf: embs bf16 padded.
__global__ void prep(const float* __restrict__ Wix, const float* __restrict__ Wfx,
                     const float* __restrict__ Wux, const float* __restrict__ Wox,
                     const float* __restrict__ bix, const float* __restrict__ bfx,
                     const float* __restrict__ bux, const float* __restrict__ box,
                     const float* __restrict__ Wih, const float* __restrict__ Wfh,
                     const float* __restrict__ Wuh, const float* __restrict__ Woh,
                     const float* __restrict__ bfh,
                     const float* __restrict__ embs,
                     unsigned short* __restrict__ W4xT, unsigned short* __restrict__ W4hT,
                     float* __restrict__ b4x, float* __restrict__ b4hf,
                     unsigned short* __restrict__ Abf)
{
    if (blockIdx.x < 256) {
        int tid = blockIdx.x * 256 + threadIdx.x;
        const int stride = 256 * 256;
        for (int idx = tid; idx < GW * KXP; idx += stride) {
            int c = idx / KXP, k = idx - c * KXP;
            int j = c >> 2, g = c & 3;
            const float* W = (g == 0) ? Wix : (g == 1) ? Wfx : (g == 2) ? Wux : Wox;
            W4xT[idx] = (j < MEM && k < KX) ? f2bf(W[k * MEM + j]) : (unsigned short)0;
        }
        for (int idx = tid; idx < GW * KH; idx += stride) {
            int c = idx / KH, k = idx - c * KH;
            int j = c >> 2, g = c & 3;
            const float* W = (g == 0) ? Wih : (g == 1) ? Wfh : (g == 2) ? Wuh : Woh;
            W4hT[idx] = (j < MEM && k < MEM) ? f2bf(W[k * MEM + j]) : (unsigned short)0;
        }
        for (int idx = tid; idx < GW; idx += stride) {
            int j = idx >> 2, g = idx & 3;
            const float* b = (g == 0) ? bix : (g == 1) ? bfx : (g == 2) ? bux : box;
            b4x[idx]  = (j < MEM) ? b[j] : 0.0f;
            b4hf[idx] = (g == 1 && j < MEM) ? bfh[j] : 0.0f;
        }
    } else {
        int idx = (blockIdx.x - 256) * 256 + threadIdx.x;
        if (idx >= NTOT * (KXP / 8)) return;
        int n = idx / (KXP / 8), c = idx - n * (KXP / 8);
        int c0 = c * 8;
        unsigned short v[8];
        if (c0 + 8 <= KX) {
            const float4* p = (const float4*)(embs + (size_t)n * KX + c0);
            float4 f0 = p[0], f1 = p[1];
            v[0]=f2bf(f0.x); v[1]=f2bf(f0.y); v[2]=f2bf(f0.z); v[3]=f2bf(f0.w);
            v[4]=f2bf(f1.x); v[5]=f2bf(f1.y); v[6]=f2bf(f1.z); v[7]=f2bf(f1.w);
        } else {
            const float* row = embs + (size_t)n * KX;
            #pragma unroll
            for (int j = 0; j < 8; ++j) {
                int col = c0 + j;
                v[j] = (col < KX) ? f2bf(row[col]) : (unsigned short)0;
            }
        }
        *(short8*)&Abf[(size_t)n * KXP + c0] = *(short8*)v;
    }
}

// ---------------- x-proj GEMM, 512 threads (8 waves), leaf-cell fused ----------
// Tile 128x128, BK=32, 2-buffer, one barrier pair per K-step. 8 waves of
// 64x32 sub-tiles double the waves per 32KB LDS allocation vs the 256-thread
// variant (occupancy was the measured limiter: 28%).
__global__ __launch_bounds__(512) void gemm_xproj(
    const unsigned short* __restrict__ A,
    const unsigned short* __restrict__ BT,
    const float* __restrict__ bias,
    unsigned short* __restrict__ PG,
    const float* __restrict__ bih, const float* __restrict__ buh,
    const float* __restrict__ boh,
    float* __restrict__ outLeaf, float* __restrict__ CLeaf,
    unsigned short* __restrict__ HbfLeaf)
{
    __shared__ __align__(16) unsigned short lds[16384];   // As[2]|Bs[2] / epi tile
    unsigned short* As = lds;          // [2][4096]
    unsigned short* Bs = lds + 8192;   // [2][4096]

    // bijective XCD swizzle (m204)
    const int nwg = gridDim.x;
    const int orig = blockIdx.x;
    const int qq = nwg >> 3, rr = nwg & 7;
    const int xcd = orig & 7, lin = orig >> 3;
    const int dd = (xcd < rr ? xcd * (qq + 1) : rr * (qq + 1) + (xcd - rr) * qq) + lin;
    const int mtile = dd / 5, ntile = dd - mtile * 5;

    const int t = threadIdx.x;
    const int m0 = mtile * 128, n0 = ntile * 128;
    const int l = t & 63, w = t >> 6;            // 8 waves
    const int l15 = l & 15, q = l >> 4;
    const int wm = (w & 1) * 64, wn = (w >> 1) * 32;

    // staging: thread t covers one 16B chunk of the 128x32 tile.
    // row = t>>2, k-chunk = t&3, source k-chunk XOR (row&3) (rule #21).
    const int srow = t >> 2;
    const int scol = ((t & 3) ^ (srow & 3)) * 8;
    int gr0 = m0 + srow; if (gr0 >= NTOT) gr0 = NTOT - 1;
    const unsigned short* a0 = A + (size_t)gr0 * KXP + scol;
    const unsigned short* b0 = BT + (size_t)(n0 + srow) * KXP + scol;

    f32x4 acc[4][2];
    #pragma unroll
    for (int i = 0; i < 4; ++i)
        #pragma unroll
        for (int j = 0; j < 2; ++j)
            acc[i][j] = (f32x4){0.f, 0.f, 0.f, 0.f};

    gl_lds16(a0, As + t * 8);
    gl_lds16(b0, Bs + t * 8);
    __syncthreads();

    int cur = 0;
    const int kiters = KXP >> 5;   // 10
    for (int kt = 0; kt < kiters; ++kt) {
        if (kt + 1 < kiters) {
            const int ko = (kt + 1) << 5;
            const int nb = cur ^ 1;
            gl_lds16(a0 + ko, As + nb * 4096 + t * 8);
            gl_lds16(b0 + ko, Bs + nb * 4096 + t * 8);
        }
        short8 a[4], b[2];
        const int csw = (q ^ (l15 & 3)) * 8;
        #pragma unroll
        for (int i = 0; i < 4; ++i)
            a[i] = *(const short8*)&As[cur * 4096 + (wm + i * 16 + l15) * 32 + csw];
        #pragma unroll
        for (int j = 0; j < 2; ++j)
            b[j] = *(const short8*)&Bs[cur * 4096 + (wn + j * 16 + l15) * 32 + csw];
        #pragma unroll
        for (int i = 0; i < 4; ++i)
            #pragma unroll
            for (int j = 0; j < 2; ++j)
                acc[i][j] = __builtin_amdgcn_mfma_f32_16x16x32_bf16(a[i], b[j], acc[i][j], 0, 0, 0);
        __syncthreads();
        cur ^= 1;
    }

    // ---- epilogue: bias + bf16 into LDS tile [128][128] ----
    float bj[2];
    #pragma unroll
    for (int j = 0; j < 2; ++j) bj[j] = bias[n0 + wn + j * 16 + l15];
    #pragma unroll
    for (int i = 0; i < 4; ++i)
        #pragma unroll
        for (int j = 0; j < 2; ++j)
            #pragma unroll
            for (int r = 0; r < 4; ++r)
                lds[(wm + i * 16 + q * 4 + r) * 128 + wn + j * 16 + l15] =
                    f2bf(acc[i][j][r] + bj[j]);
    __syncthreads();

    if (m0 < NLEAF) {
        // leaf LSTM cell: tile holds cols 4*j+g for j in [32*ntile, +32)
        #pragma unroll
        for (int s = 0; s < 8; ++s) {
            int idx = (s << 9) + t;
            int row = idx >> 5, jl = idx & 31;
            int grow = m0 + row;
            int j = ntile * 32 + jl;
            const unsigned short* g4 = &lds[row * 128 + jl * 4];
            if (j < MEM) {
                float gi = bf2f(g4[0]) + bih[j];
                float gu = bf2f(g4[2]) + buh[j];
                float go = bf2f(g4[3]) + boh[j];
                float iv = sigf(gi), uv = tanhf_fast(gu), ov = sigf(go);
                float c = iv * uv;
                float h = ov * tanhf_fast(c);
                outLeaf[(size_t)grow * MEM + j] = h;
                CLeaf[(size_t)grow * MEM + j] = c;
                HbfLeaf[(size_t)grow * KH + j] = f2bf(h);
            } else if (j < KH) {
                HbfLeaf[(size_t)grow * KH + j] = 0;
            }
        }
    } else {
        int row = t >> 2, qd = t & 3;
        int grow = m0 + row;
        if (grow < NTOT) {
            const unsigned short* src = &lds[row * 128 + qd * 32];
            unsigned short* dst = PG + (size_t)grow * GW + n0 + qd * 32;
            #pragma unroll
            for (int c8 = 0; c8 < 4; ++c8)
                *(short8*)(dst + c8 * 8) = *(const short8*)(src + c8 * 8);
        }
    }
}

// ---------------- level GEMM, 512 threads, fully-fused cell epilogue -----------
__global__ __launch_bounds__(512) void gemm_level(
    const unsigned short* __restrict__ Hprev, int nprev, int npar,
    const unsigned short* __restrict__ BT, const float* __restrict__ bias,
    const unsigned short* __restrict__ P,     // this level's x-proj rows
    const float* __restrict__ Cprev,
    const float* __restrict__ bih, const float* __restrict__ buh,
    const float* __restrict__ boh,
    float* __restrict__ outRow, float* __restrict__ Crow,
    unsigned short* __restrict__ HbfRow)
{
    __shared__ __align__(16) unsigned short lds[16384];
    unsigned short* As = lds;
    unsigned short* Bs = lds + 8192;

    const int nwg = gridDim.x;
    const int orig = blockIdx.x;
    const int qq = nwg >> 3, rr = nwg & 7;
    const int xcd = orig & 7, lin = orig >> 3;
    const int dd = (xcd < rr ? xcd * (qq + 1) : rr * (qq + 1) + (xcd - rr) * qq) + lin;
    const int mtile = dd / 5, ntile = dd - mtile * 5;

    const int t = threadIdx.x;
    const int m0 = mtile * 128, n0 = ntile * 128;
    const int l = t & 63, w = t >> 6;
    const int l15 = l & 15, q = l >> 4;
    const int wm = (w & 1) * 64, wn = (w >> 1) * 32;

    const int srow = t >> 2;
    const int scol = ((t & 3) ^ (srow & 3)) * 8;
    int gr0 = m0 + srow; if (gr0 >= nprev) gr0 = nprev - 1;
    const unsigned short* a0 = Hprev + (size_t)gr0 * KH + scol;
    const unsigned short* b0 = BT + (size_t)(n0 + srow) * KH + scol;

    f32x4 acc[4][2];
    #pragma unroll
    for (int i = 0; i < 4; ++i)
        #pragma unroll
        for (int j = 0; j < 2; ++j)
            acc[i][j] = (f32x4){0.f, 0.f, 0.f, 0.f};

    gl_lds16(a0, As + t * 8);
    gl_lds16(b0, Bs + t * 8);
    __syncthreads();

    int cur = 0;
    const int kiters = KH >> 5;   // 5
    for (int kt = 0; kt < kiters; ++kt) {
        if (kt + 1 < kiters) {
            const int ko = (kt + 1) << 5;
            const int nb = cur ^ 1;
            gl_lds16(a0 + ko, As + nb * 4096 + t * 8);
            gl_lds16(b0 + ko, Bs + nb * 4096 + t * 8);
        }
        short8 a[4], b[2];
        const int csw = (q ^ (l15 & 3)) * 8;
        #pragma unroll
        for (int i = 0; i < 4; ++i)
            a[i] = *(const short8*)&As[cur * 4096 + (wm + i * 16 + l15) * 32 + csw];
        #pragma unroll
        for (int j = 0; j < 2; ++j)
            b[j] = *(const short8*)&Bs[cur * 4096 + (wn + j * 16 + l15) * 32 + csw];
        #pragma unroll
        for (int i = 0; i < 4; ++i)
            #pragma unroll
            for (int j = 0; j < 2; ++j)
                acc[i][j] = __builtin_amdgcn_mfma_f32_16x16x32_bf16(a[i], b[j], acc[i][j], 0, 0, 0);
        __syncthreads();
        cur ^= 1;
    }

    // ---- per-child preacts (bf16, f-bias applied) into LDS tile [128][128] ----
    float bj[2];
    #pragma unroll
    for (int j = 0; j < 2; ++j) bj[j] = bias[n0 + wn + j * 16 + l15];
    #pragma unroll
    for (int i = 0; i < 4; ++i)
        #pragma unroll
        for (int j = 0; j < 2; ++j)
            #pragma unroll
            for (int r = 0; r < 4; ++r)
                lds[(wm + i * 16 + q * 4 + r) * 128 + wn + j * 16 + l15] =
                    f2bf(acc[i][j][r] + bj[j]);
    __syncthreads();

    // ---- fused cell: 32 parents x 32 features per block ----
    const int pp0 = m0 >> 2;
    #pragma unroll
    for (int s = 0; s < 2; ++s) {
        int idx = (s << 9) + t;          // 0..1023
        int pl = idx >> 5, jl = idx & 31;
        int par = pp0 + pl;
        if (par >= npar) continue;
        int j = ntile * 32 + jl;
        if (j < MEM) {
            const unsigned short* xr = P + (size_t)par * GW + 4 * j;
            float ip = bf2f(xr[0]) + bih[j];
            float fx = bf2f(xr[1]);
            float up = bf2f(xr[2]) + buh[j];
            float op = bf2f(xr[3]) + boh[j];
            float fc = 0.0f;
            #pragma unroll
            for (int k = 0; k < 4; ++k) {
                const unsigned short* g4 = &lds[(pl * 4 + k) * 128 + jl * 4];
                ip += bf2f(g4[0]);
                up += bf2f(g4[2]);
                op += bf2f(g4[3]);
                float f = sigf(fx + bf2f(g4[1]));
                fc += f * Cprev[(size_t)(4 * par + k) * MEM + j];
            }
            float iv = sigf(ip), uv = tanhf_fast(up), ov = sigf(op);
            float c = iv * uv + fc;
            float h = ov * tanhf_fast(c);
            outRow[(size_t)par * MEM + j] = h;
            Crow[(size_t)par * MEM + j] = c;
            HbfRow[(size_t)par * KH + j] = f2bf(h);
        } else if (j < KH) {
            HbfRow[(size_t)par * KH + j] = 0;
        }
    }
}

extern "C" void kernel_launch(void* const* d_in, const int* in_sizes, int n_in,
                              void* d_out, int out_size, void* d_ws, size_t ws_size,
                              hipStream_t stream)
{
    (void)in_sizes; (void)n_in; (void)out_size;
    const float* embs = (const float*)d_in[0];
    const float* Wix = (const float*)d_in[1];  const float* bix = (const float*)d_in[2];
    const float* Wfx = (const float*)d_in[3];  const float* bfx = (const float*)d_in[4];
    const float* Wux = (const float*)d_in[5];  const float* bux = (const float*)d_in[6];
    const float* Wox = (const float*)d_in[7];  const float* box = (const float*)d_in[8];
    const float* Wih = (const float*)d_in[9];  const float* bih = (const float*)d_in[10];
    const float* Wfh = (const float*)d_in[11]; const float* bfh = (const float*)d_in[12];
    const float* Wuh = (const float*)d_in[13]; const float* buh = (const float*)d_in[14];
    const float* Woh = (const float*)d_in[15]; const float* boh = (const float*)d_in[16];
    float* out = (float*)d_out;

    char* p = (char*)d_ws;
    auto alloc = [&](size_t bytes) -> char* {
        char* r = p;
        p += (bytes + 255) & ~(size_t)255;
        return r;
    };
    unsigned short* PG   = (unsigned short*)alloc((size_t)NTOT * GW * 2);   // 111.8 MB
    float*          C    = (float*)alloc((size_t)NTOT * MEM * 4);           //  52.4 MB
    unsigned short* Hbf  = (unsigned short*)alloc((size_t)NTOT * KH * 2);   //  28.0 MB
    unsigned short* W4xT = (unsigned short*)alloc((size_t)GW * KXP * 2);
    unsigned short* W4hT = (unsigned short*)alloc((size_t)GW * KH * 2);
    float*          b4x  = (float*)alloc(GW * 4);
    float*          b4hf = (float*)alloc(GW * 4);
    if ((size_t)(p - (char*)d_ws) > ws_size) return;

    // Abf (bf16 embs, NTOT*KXP = 55.9 MB) aliases PG's LEAF region (bytes
    // [0, 83.9 MB)): the x-proj GEMM reads Abf while writing only internal PG
    // rows (byte offset >= NLEAF*GW*2 = 83.9 MB); leaf cells go direct to
    // out/C/Hbf. The leaf PG region is otherwise dead.
    unsigned short* Abf = PG;

    {
        int convBlocks = (NTOT * (KXP / 8) + 255) / 256;
        prep<<<256 + convBlocks, 256, 0, stream>>>(
            Wix, Wfx, Wux, Wox, bix, bfx, bux, box,
            Wih, Wfh, Wuh, Woh, bfh, embs,
            W4xT, W4hT, b4x, b4hf, Abf);
    }

    // x-projections for ALL nodes; leaf cells fused in-epilogue
    {
        int mt = (NTOT + 127) / 128;
        gemm_xproj<<<mt * 5, 512, 0, stream>>>(
            Abf, W4xT, b4x, PG, bih, buh, boh, out, C, Hbf);
    }

    // levels: one fused GEMM+cell dispatch each
    for (int d = 1; d < DEPTH; ++d) {
        int nprev = SIZES[d - 1];
        int n = SIZES[d];
        int mt = (nprev + 127) / 128;
        gemm_level<<<mt * 5, 512, 0, stream>>>(
            Hbf + (size_t)OFF[d - 1] * KH, nprev, n,
            W4hT, b4hf,
            PG + (size_t)OFF[d] * GW,
            C + (size_t)OFF[d - 1] * MEM,
            bih, buh, boh,
            out + (size_t)OFF[d] * MEM, C + (size_t)OFF[d] * MEM,
            Hbf + (size_t)OFF[d] * KH);
    }
}

// Round 8
// 345.503 us; speedup vs baseline: 1.3157x; 1.0126x over previous
//
#include <hip/hip_runtime.h>

#define MEM    150
#define GW     640   // 4 gates interleaved: col = 4*j + g  (g: 0=i,1=f,2=u,3=o)
#define KX     300   // x-proj real K
#define KXP    320   // x-proj padded K (bf16 A buffer pitch)
#define KH     160   // level GEMM K (padded, H buffer is pre-padded)
#define NLEAF  65536
#define NTOT   87381
#define DEPTH  9

static const int SIZES[DEPTH] = {65536,16384,4096,1024,256,64,16,4,1};
static const int OFF[DEPTH]   = {0,65536,81920,86016,87040,87296,87360,87376,87380};

typedef __attribute__((ext_vector_type(8))) short short8;
typedef __attribute__((ext_vector_type(4))) float f32x4;

__device__ __forceinline__ float sigf(float x) { return 1.0f / (1.0f + __expf(-x)); }
__device__ __forceinline__ float tanhf_fast(float x) {
    float e = __expf(2.0f * x);
    return 1.0f - 2.0f / (e + 1.0f);
}
__device__ __forceinline__ unsigned short f2bf(float f) {
    union { float f; unsigned u; } v; v.f = f;
    unsigned r = v.u + 0x7FFF + ((v.u >> 16) & 1);
    return (unsigned short)(r >> 16);
}
__device__ __forceinline__ float bf2f(unsigned short u) {
    union { unsigned u; float f; } v; v.u = ((unsigned)u) << 16; return v.f;
}

// async global->LDS, 16 bytes per lane
typedef const __attribute__((address_space(1))) unsigned int* as1_u32p;
typedef __attribute__((address_space(3))) unsigned int* as3_u32p;
__device__ __forceinline__ void gl_lds16(const unsigned short* g, unsigned short* l) {
    __builtin_amdgcn_global_load_lds((as1_u32p)g, (as3_u32p)l, 16, 0, 0);
}

// ---------------- prep: weight packing + embs conversion (one dispatch) --------
// W4xT: 640 x KXP, row c=4j+g from W_gx[k][j]; W4hT: 640 x KH same layout.
// b4x[4j+g]=b_gx[j]; b4hf[4j+g]=(g==1)?bfh[j]:0. Abf: embs bf16 padded.
__global__ void prep(const float* __restrict__ Wix, const float* __restrict__ Wfx,
                     const float* __restrict__ Wux, const float* __restrict__ Wox,
                     const float* __restrict__ bix, const float* __restrict__ bfx,
                     const float* __restrict__ bux, const float* __restrict__ box,
                     const float* __restrict__ Wih, const float* __restrict__ Wfh,
                     const float* __restrict__ Wuh, const float* __restrict__ Woh,
                     const float* __restrict__ bfh,
                     const float* __restrict__ embs,
                     unsigned short* __restrict__ W4xT, unsigned short* __restrict__ W4hT,
                     float* __restrict__ b4x, float* __restrict__ b4hf,
                     unsigned short* __restrict__ Abf)
{
    if (blockIdx.x < 256) {
        int tid = blockIdx.x * 256 + threadIdx.x;
        const int stride = 256 * 256;
        for (int idx = tid; idx < GW * KXP; idx += stride) {
            int c = idx / KXP, k = idx - c * KXP;
            int j = c >> 2, g = c & 3;
            const float* W = (g == 0) ? Wix : (g == 1) ? Wfx : (g == 2) ? Wux : Wox;
            W4xT[idx] = (j < MEM && k < KX) ? f2bf(W[k * MEM + j]) : (unsigned short)0;
        }
        for (int idx = tid; idx < GW * KH; idx += stride) {
            int c = idx / KH, k = idx - c * KH;
            int j = c >> 2, g = c & 3;
            const float* W = (g == 0) ? Wih : (g == 1) ? Wfh : (g == 2) ? Wuh : Woh;
            W4hT[idx] = (j < MEM && k < MEM) ? f2bf(W[k * MEM + j]) : (unsigned short)0;
        }
        for (int idx = tid; idx < GW; idx += stride) {
            int j = idx >> 2, g = idx & 3;
            const float* b = (g == 0) ? bix : (g == 1) ? bfx : (g == 2) ? bux : box;
            b4x[idx]  = (j < MEM) ? b[j] : 0.0f;
            b4hf[idx] = (g == 1 && j < MEM) ? bfh[j] : 0.0f;
        }
    } else {
        int idx = (blockIdx.x - 256) * 256 + threadIdx.x;
        if (idx >= NTOT * (KXP / 8)) return;
        int n = idx / (KXP / 8), c = idx - n * (KXP / 8);
        int c0 = c * 8;
        unsigned short v[8];
        if (c0 + 8 <= KX) {
            const float4* p = (const float4*)(embs + (size_t)n * KX + c0);
            float4 f0 = p[0], f1 = p[1];
            v[0]=f2bf(f0.x); v[1]=f2bf(f0.y); v[2]=f2bf(f0.z); v[3]=f2bf(f0.w);
            v[4]=f2bf(f1.x); v[5]=f2bf(f1.y); v[6]=f2bf(f1.z); v[7]=f2bf(f1.w);
        } else {
            const float* row = embs + (size_t)n * KX;
            #pragma unroll
            for (int j = 0; j < 8; ++j) {
                int col = c0 + j;
                v[j] = (col < KX) ? f2bf(row[col]) : (unsigned short)0;
            }
        }
        *(short8*)&Abf[(size_t)n * KXP + c0] = *(short8*)v;
    }
}

// ---------------- x-proj GEMM, 512 threads, counted-vmcnt 2-buffer pipeline ----
// Tile 128x128, BK=32, 2 LDS buffers (32KB). Per K-step: issue prefetch ->
// s_waitcnt vmcnt(2) (wait ONLY previous stage; this stage's 2 loads stay in
// flight across the MFMA phase) -> s_barrier -> ds_read+MFMA -> s_barrier
// (protects buffer reuse). Removes the per-step vmcnt(0) drain at zero LDS
// cost (R5's pipeline paid 2x LDS and lost occupancy; this doesn't).
__global__ __launch_bounds__(512) void gemm_xproj(
    const unsigned short* __restrict__ A,
    const unsigned short* __restrict__ BT,
    const float* __restrict__ bias,
    unsigned short* __restrict__ PG,
    const float* __restrict__ bih, const float* __restrict__ buh,
    const float* __restrict__ boh,
    float* __restrict__ outLeaf, float* __restrict__ CLeaf,
    unsigned short* __restrict__ HbfLeaf)
{
    __shared__ __align__(16) unsigned short lds[16384];   // As[2]|Bs[2] / epi tile
    unsigned short* As = lds;          // [2][4096]
    unsigned short* Bs = lds + 8192;   // [2][4096]

    // bijective XCD swizzle (m204)
    const int nwg = gridDim.x;
    const int orig = blockIdx.x;
    const int qq = nwg >> 3, rr = nwg & 7;
    const int xcd = orig & 7, lin = orig >> 3;
    const int dd = (xcd < rr ? xcd * (qq + 1) : rr * (qq + 1) + (xcd - rr) * qq) + lin;
    const int mtile = dd / 5, ntile = dd - mtile * 5;

    const int t = threadIdx.x;
    const int m0 = mtile * 128, n0 = ntile * 128;
    const int l = t & 63, w = t >> 6;            // 8 waves
    const int l15 = l & 15, q = l >> 4;
    const int wm = (w & 1) * 64, wn = (w >> 1) * 32;

    // staging: thread t covers one 16B chunk of the 128x32 tile.
    // row = t>>2, k-chunk = t&3, source k-chunk XOR (row&3) (rule #21).
    const int srow = t >> 2;
    const int scol = ((t & 3) ^ (srow & 3)) * 8;
    int gr0 = m0 + srow; if (gr0 >= NTOT) gr0 = NTOT - 1;
    const unsigned short* a0 = A + (size_t)gr0 * KXP + scol;
    const unsigned short* b0 = BT + (size_t)(n0 + srow) * KXP + scol;

    f32x4 acc[4][2];
    #pragma unroll
    for (int i = 0; i < 4; ++i)
        #pragma unroll
        for (int j = 0; j < 2; ++j)
            acc[i][j] = (f32x4){0.f, 0.f, 0.f, 0.f};

    // prologue: issue stage 0 (no wait — first iteration's vmcnt covers it)
    gl_lds16(a0, As + t * 8);
    gl_lds16(b0, Bs + t * 8);

    int cur = 0;
    const int kiters = KXP >> 5;   // 10
    for (int kt = 0; kt < kiters; ++kt) {
        if (kt + 1 < kiters) {
            const int ko = (kt + 1) << 5;
            const int nb = cur ^ 1;
            gl_lds16(a0 + ko, As + nb * 4096 + t * 8);
            gl_lds16(b0 + ko, Bs + nb * 4096 + t * 8);
            __builtin_amdgcn_sched_barrier(0);             // pin issue before wait
            asm volatile("s_waitcnt vmcnt(2)" ::: "memory"); // stage kt landed
        } else {
            asm volatile("s_waitcnt vmcnt(0)" ::: "memory");
        }
        __builtin_amdgcn_s_barrier();
        __builtin_amdgcn_sched_barrier(0);                 // rule #18: no hoist

        short8 a[4], b[2];
        const int csw = (q ^ (l15 & 3)) * 8;
        #pragma unroll
        for (int i = 0; i < 4; ++i)
            a[i] = *(const short8*)&As[cur * 4096 + (wm + i * 16 + l15) * 32 + csw];
        #pragma unroll
        for (int j = 0; j < 2; ++j)
            b[j] = *(const short8*)&Bs[cur * 4096 + (wn + j * 16 + l15) * 32 + csw];
        __builtin_amdgcn_s_setprio(1);
        #pragma unroll
        for (int i = 0; i < 4; ++i)
            #pragma unroll
            for (int j = 0; j < 2; ++j)
                acc[i][j] = __builtin_amdgcn_mfma_f32_16x16x32_bf16(a[i], b[j], acc[i][j], 0, 0, 0);
        __builtin_amdgcn_s_setprio(0);
        __builtin_amdgcn_sched_barrier(0);                 // keep reads in phase
        __builtin_amdgcn_s_barrier();                      // buffer-reuse guard
        cur ^= 1;
    }

    // ---- epilogue: bias + bf16 into LDS tile [128][128] ----
    float bj[2];
    #pragma unroll
    for (int j = 0; j < 2; ++j) bj[j] = bias[n0 + wn + j * 16 + l15];
    #pragma unroll
    for (int i = 0; i < 4; ++i)
        #pragma unroll
        for (int j = 0; j < 2; ++j)
            #pragma unroll
            for (int r = 0; r < 4; ++r)
                lds[(wm + i * 16 + q * 4 + r) * 128 + wn + j * 16 + l15] =
                    f2bf(acc[i][j][r] + bj[j]);
    __syncthreads();

    if (m0 < NLEAF) {
        // leaf LSTM cell: tile holds cols 4*j+g for j in [32*ntile, +32)
        #pragma unroll
        for (int s = 0; s < 8; ++s) {
            int idx = (s << 9) + t;
            int row = idx >> 5, jl = idx & 31;
            int grow = m0 + row;
            int j = ntile * 32 + jl;
            const unsigned short* g4 = &lds[row * 128 + jl * 4];
            if (j < MEM) {
                float gi = bf2f(g4[0]) + bih[j];
                float gu = bf2f(g4[2]) + buh[j];
                float go = bf2f(g4[3]) + boh[j];
                float iv = sigf(gi), uv = tanhf_fast(gu), ov = sigf(go);
                float c = iv * uv;
                float h = ov * tanhf_fast(c);
                outLeaf[(size_t)grow * MEM + j] = h;
                CLeaf[(size_t)grow * MEM + j] = c;
                HbfLeaf[(size_t)grow * KH + j] = f2bf(h);
            } else if (j < KH) {
                HbfLeaf[(size_t)grow * KH + j] = 0;
            }
        }
    } else {
        int row = t >> 2, qd = t & 3;
        int grow = m0 + row;
        if (grow < NTOT) {
            const unsigned short* src = &lds[row * 128 + qd * 32];
            unsigned short* dst = PG + (size_t)grow * GW + n0 + qd * 32;
            #pragma unroll
            for (int c8 = 0; c8 < 4; ++c8)
                *(short8*)(dst + c8 * 8) = *(const short8*)(src + c8 * 8);
        }
    }
}

// ---------------- level GEMM, 512 threads, counted-vmcnt + fused cell ----------
__global__ __launch_bounds__(512) void gemm_level(
    const unsigned short* __restrict__ Hprev, int nprev, int npar,
    const unsigned short* __restrict__ BT, const float* __restrict__ bias,
    const unsigned short* __restrict__ P,     // this level's x-proj rows
    const float* __restrict__ Cprev,
    const float* __restrict__ bih, const float* __restrict__ buh,
    const float* __restrict__ boh,
    float* __restrict__ outRow, float* __restrict__ Crow,
    unsigned short* __restrict__ HbfRow)
{
    __shared__ __align__(16) unsigned short lds[16384];
    unsigned short* As = lds;
    unsigned short* Bs = lds + 8192;

    const int nwg = gridDim.x;
    const int orig = blockIdx.x;
    const int qq = nwg >> 3, rr = nwg & 7;
    const int xcd = orig & 7, lin = orig >> 3;
    const int dd = (xcd < rr ? xcd * (qq + 1) : rr * (qq + 1) + (xcd - rr) * qq) + lin;
    const int mtile = dd / 5, ntile = dd - mtile * 5;

    const int t = threadIdx.x;
    const int m0 = mtile * 128, n0 = ntile * 128;
    const int l = t & 63, w = t >> 6;
    const int l15 = l & 15, q = l >> 4;
    const int wm = (w & 1) * 64, wn = (w >> 1) * 32;

    const int srow = t >> 2;
    const int scol = ((t & 3) ^ (srow & 3)) * 8;
    int gr0 = m0 + srow; if (gr0 >= nprev) gr0 = nprev - 1;
    const unsigned short* a0 = Hprev + (size_t)gr0 * KH + scol;
    const unsigned short* b0 = BT + (size_t)(n0 + srow) * KH + scol;

    f32x4 acc[4][2];
    #pragma unroll
    for (int i = 0; i < 4; ++i)
        #pragma unroll
        for (int j = 0; j < 2; ++j)
            acc[i][j] = (f32x4){0.f, 0.f, 0.f, 0.f};

    gl_lds16(a0, As + t * 8);
    gl_lds16(b0, Bs + t * 8);

    int cur = 0;
    const int kiters = KH >> 5;   // 5
    for (int kt = 0; kt < kiters; ++kt) {
        if (kt + 1 < kiters) {
            const int ko = (kt + 1) << 5;
            const int nb = cur ^ 1;
            gl_lds16(a0 + ko, As + nb * 4096 + t * 8);
            gl_lds16(b0 + ko, Bs + nb * 4096 + t * 8);
            __builtin_amdgcn_sched_barrier(0);
            asm volatile("s_waitcnt vmcnt(2)" ::: "memory");
        } else {
            asm volatile("s_waitcnt vmcnt(0)" ::: "memory");
        }
        __builtin_amdgcn_s_barrier();
        __builtin_amdgcn_sched_barrier(0);

        short8 a[4], b[2];
        const int csw = (q ^ (l15 & 3)) * 8;
        #pragma unroll
        for (int i = 0; i < 4; ++i)
            a[i] = *(const short8*)&As[cur * 4096 + (wm + i * 16 + l15) * 32 + csw];
        #pragma unroll
        for (int j = 0; j < 2; ++j)
            b[j] = *(const short8*)&Bs[cur * 4096 + (wn + j * 16 + l15) * 32 + csw];
        __builtin_amdgcn_s_setprio(1);
        #pragma unroll
        for (int i = 0; i < 4; ++i)
            #pragma unroll
            for (int j = 0; j < 2; ++j)
                acc[i][j] = __builtin_amdgcn_mfma_f32_16x16x32_bf16(a[i], b[j], acc[i][j], 0, 0, 0);
        __builtin_amdgcn_s_setprio(0);
        __builtin_amdgcn_sched_barrier(0);
        __builtin_amdgcn_s_barrier();
        cur ^= 1;
    }

    // ---- per-child preacts (bf16, f-bias applied) into LDS tile [128][128] ----
    float bj[2];
    #pragma unroll
    for (int j = 0; j < 2; ++j) bj[j] = bias[n0 + wn + j * 16 + l15];
    #pragma unroll
    for (int i = 0; i < 4; ++i)
        #pragma unroll
        for (int j = 0; j < 2; ++j)
            #pragma unroll
            for (int r = 0; r < 4; ++r)
                lds[(wm + i * 16 + q * 4 + r) * 128 + wn + j * 16 + l15] =
                    f2bf(acc[i][j][r] + bj[j]);
    __syncthreads();

    // ---- fused cell: 32 parents x 32 features per block ----
    const int pp0 = m0 >> 2;
    #pragma unroll
    for (int s = 0; s < 2; ++s) {
        int idx = (s << 9) + t;          // 0..1023
        int pl = idx >> 5, jl = idx & 31;
        int par = pp0 + pl;
        if (par >= npar) continue;
        int j = ntile * 32 + jl;
        if (j < MEM) {
            const unsigned short* xr = P + (size_t)par * GW + 4 * j;
            float ip = bf2f(xr[0]) + bih[j];
            float fx = bf2f(xr[1]);
            float up = bf2f(xr[2]) + buh[j];
            float op = bf2f(xr[3]) + boh[j];
            float fc = 0.0f;
            #pragma unroll
            for (int k = 0; k < 4; ++k) {
                const unsigned short* g4 = &lds[(pl * 4 + k) * 128 + jl * 4];
                ip += bf2f(g4[0]);
                up += bf2f(g4[2]);
                op += bf2f(g4[3]);
                float f = sigf(fx + bf2f(g4[1]));
                fc += f * Cprev[(size_t)(4 * par + k) * MEM + j];
            }
            float iv = sigf(ip), uv = tanhf_fast(up), ov = sigf(op);
            float c = iv * uv + fc;
            float h = ov * tanhf_fast(c);
            outRow[(size_t)par * MEM + j] = h;
            Crow[(size_t)par * MEM + j] = c;
            HbfRow[(size_t)par * KH + j] = f2bf(h);
        } else if (j < KH) {
            HbfRow[(size_t)par * KH + j] = 0;
        }
    }
}

extern "C" void kernel_launch(void* const* d_in, const int* in_sizes, int n_in,
                              void* d_out, int out_size, void* d_ws, size_t ws_size,
                              hipStream_t stream)
{
    (void)in_sizes; (void)n_in; (void)out_size;
    const float* embs = (const float*)d_in[0];
    const float* Wix = (const float*)d_in[1];  const float* bix = (const float*)d_in[2];
    const float* Wfx = (const float*)d_in[3];  const float* bfx = (const float*)d_in[4];
    const float* Wux = (const float*)d_in[5];  const float* bux = (const float*)d_in[6];
    const float* Wox = (const float*)d_in[7];  const float* box = (const float*)d_in[8];
    const float* Wih = (const float*)d_in[9];  const float* bih = (const float*)d_in[10];
    const float* Wfh = (const float*)d_in[11]; const float* bfh = (const float*)d_in[12];
    const float* Wuh = (const float*)d_in[13]; const float* buh = (const float*)d_in[14];
    const float* Woh = (const float*)d_in[15]; const float* boh = (const float*)d_in[16];
    float* out = (float*)d_out;

    char* p = (char*)d_ws;
    auto alloc = [&](size_t bytes) -> char* {
        char* r = p;
        p += (bytes + 255) & ~(size_t)255;
        return r;
    };
    unsigned short* PG   = (unsigned short*)alloc((size_t)NTOT * GW * 2);   // 111.8 MB
    float*          C    = (float*)alloc((size_t)NTOT * MEM * 4);           //  52.4 MB
    unsigned short* Hbf  = (unsigned short*)alloc((size_t)NTOT * KH * 2);   //  28.0 MB
    unsigned short* W4xT = (unsigned short*)alloc((size_t)GW * KXP * 2);
    unsigned short* W4hT = (unsigned short*)alloc((size_t)GW * KH * 2);
    float*          b4x  = (float*)alloc(GW * 4);
    float*          b4hf = (float*)alloc(GW * 4);
    if ((size_t)(p - (char*)d_ws) > ws_size) return;

    // Abf (bf16 embs, NTOT*KXP = 55.9 MB) aliases PG's LEAF region (bytes
    // [0, 83.9 MB)): the x-proj GEMM reads Abf while writing only internal PG
    // rows (byte offset >= NLEAF*GW*2 = 83.9 MB); leaf cells go direct to
    // out/C/Hbf. The leaf PG region is otherwise dead.
    unsigned short* Abf = PG;

    {
        int convBlocks = (NTOT * (KXP / 8) + 255) / 256;
        prep<<<256 + convBlocks, 256, 0, stream>>>(
            Wix, Wfx, Wux, Wox, bix, bfx, bux, box,
            Wih, Wfh, Wuh, Woh, bfh, embs,
            W4xT, W4hT, b4x, b4hf, Abf);
    }

    // x-projections for ALL nodes; leaf cells fused in-epilogue
    {
        int mt = (NTOT + 127) / 128;
        gemm_xproj<<<mt * 5, 512, 0, stream>>>(
            Abf, W4xT, b4x, PG, bih, buh, boh, out, C, Hbf);
    }

    // levels: one fused GEMM+cell dispatch each
    for (int d = 1; d < DEPTH; ++d) {
        int nprev = SIZES[d - 1];
        int n = SIZES[d];
        int mt = (nprev + 127) / 128;
        gemm_level<<<mt * 5, 512, 0, stream>>>(
            Hbf + (size_t)OFF[d - 1] * KH, nprev, n,
            W4hT, b4hf,
            PG + (size_t)OFF[d] * GW,
            C + (size_t)OFF[d - 1] * MEM,
            bih, buh, boh,
            out + (size_t)OFF[d] * MEM, C + (size_t)OFF[d] * MEM,
            Hbf + (size_t)OFF[d] * KH);
    }
}